// Round 11
// baseline (514.059 us; speedup 1.0000x reference)
//
#include <hip/hip_runtime.h>
#include <math.h>

typedef unsigned short u16;
typedef unsigned int u32;
typedef short short8 __attribute__((ext_vector_type(8)));
typedef float f32x4 __attribute__((ext_vector_type(4)));

#define B_ 8
#define S_ 2048
#define D_ 512
#define N_ (B_ * S_)
#define ND_ ((size_t)N_ * D_)
#define CC_ 64              // chunk length (v2: 64 to amortize scan overhead)
#define NC_ (S_ / CC_)      // 32 chunks
#define SV_ 16              // v-rows per scan block
#define TB_ 8               // conv rows per block

__device__ __forceinline__ u16 f2bf(float f) {
  union { float f; u32 i; } v; v.f = f;
  u32 i = v.i;
  i += 0x7FFFu + ((i >> 16) & 1u);   // round-to-nearest-even
  return (u16)(i >> 16);
}
__device__ __forceinline__ float bf2f(u16 u) {
  union { u32 i; float f; } v; v.i = ((u32)u) << 16; return v.f;
}
__device__ __forceinline__ float sigm(float x) { return 1.0f / (1.0f + expf(-x)); }

__device__ __forceinline__ void glds16(const u16* g, u16* l) {
  __builtin_amdgcn_global_load_lds(
      (const __attribute__((address_space(1))) void*)g,
      (__attribute__((address_space(3))) void*)l, 16, 0, 0);
}

// ---------------------------------------------------------------------------
// f32 -> bf16 conversion (bulk, for x)
// ---------------------------------------------------------------------------
__global__ __launch_bounds__(256) void cvt_bf16(const float* __restrict__ s,
                                                u16* __restrict__ d, int n)
{
  const int i = (blockIdx.x * 256 + threadIdx.x) * 4;
  if (i < n) {
    const float4 v = *(const float4*)(s + i);
    ushort4 o;
    o.x = f2bf(v.x); o.y = f2bf(v.y); o.z = f2bf(v.z); o.w = f2bf(v.w);
    *(ushort4*)(d + i) = o;
  }
}

// ---------------------------------------------------------------------------
// fused f32 -> bf16 for the five 512x512 weight matrices (contiguous dst)
// ---------------------------------------------------------------------------
__global__ __launch_bounds__(256) void cvt_w5(
    const float* __restrict__ w0, const float* __restrict__ w1,
    const float* __restrict__ w2, const float* __restrict__ w3,
    const float* __restrict__ w4, u16* __restrict__ d)
{
  const int z = blockIdx.y;
  const float* s = (z == 0) ? w0 : (z == 1) ? w1 : (z == 2) ? w2 : (z == 3) ? w3 : w4;
  u16* o = d + (size_t)z * 512 * 512;
  const int i = (blockIdx.x * 256 + threadIdx.x) * 4;
  const float4 v = *(const float4*)(s + i);
  ushort4 t;
  t.x = f2bf(v.x); t.y = f2bf(v.y); t.z = f2bf(v.z); t.w = f2bf(v.w);
  *(ushort4*)(o + i) = t;
}

// ---------------------------------------------------------------------------
// GEMM core: 128x128 tile; staging via global_load_lds width=16 with k-slot
// XOR swizzle pre-applied to the global source (round-10 neutral-kept).
// ---------------------------------------------------------------------------
__device__ __forceinline__ void gemm_body(
    const u16* __restrict__ A, const u16* __restrict__ W,
    const float* __restrict__ bias, float* __restrict__ out,
    int m0, int n0, u16* As, u16* Bs)
{
  const int tid = threadIdx.x;
  const int lane = tid & 63, wave = tid >> 6;
  const int wm = (wave >> 1) * 64, wn = (wave & 1) * 64;
  const int l15 = lane & 15, quad = lane >> 4;

  const int lr = tid >> 2;
  const int ks = (tid & 3) ^ ((tid >> 3) & 3);
  u16* abase0 = As + wave * 512;
  u16* abase1 = As + 2048 + wave * 512;
  u16* bbase0 = Bs + wave * 512;
  u16* bbase1 = Bs + 2048 + wave * 512;

  f32x4 acc[4][4];
#pragma unroll
  for (int i = 0; i < 4; i++)
#pragma unroll
    for (int j = 0; j < 4; j++) acc[i][j] = (f32x4){0.f, 0.f, 0.f, 0.f};

  for (int k0 = 0; k0 < 512; k0 += 32) {
    __syncthreads();
    glds16(A + (size_t)(m0 + lr) * 512 + k0 + ks * 8, abase0);
    glds16(A + (size_t)(m0 + 64 + lr) * 512 + k0 + ks * 8, abase1);
    glds16(W + (size_t)(n0 + lr) * 512 + k0 + ks * 8, bbase0);
    glds16(W + (size_t)(n0 + 64 + lr) * 512 + k0 + ks * 8, bbase1);
    __syncthreads();
    short8 af[4], bf[4];
#pragma unroll
    for (int mt = 0; mt < 4; mt++) {
      const int row = wm + mt * 16 + l15;
      af[mt] = *(const short8*)(As + row * 32 + ((quad ^ ((row >> 1) & 3)) * 8));
    }
#pragma unroll
    for (int nt = 0; nt < 4; nt++) {
      const int row = wn + nt * 16 + l15;
      bf[nt] = *(const short8*)(Bs + row * 32 + ((quad ^ ((row >> 1) & 3)) * 8));
    }
#pragma unroll
    for (int mt = 0; mt < 4; mt++)
#pragma unroll
      for (int nt = 0; nt < 4; nt++)
        acc[mt][nt] = __builtin_amdgcn_mfma_f32_16x16x32_bf16(af[mt], bf[nt], acc[mt][nt], 0, 0, 0);
  }
#pragma unroll
  for (int mt = 0; mt < 4; mt++) {
#pragma unroll
    for (int nt = 0; nt < 4; nt++) {
      const int col = n0 + wn + nt * 16 + l15;
      const float bcol = bias[col];
#pragma unroll
      for (int r = 0; r < 4; r++) {
        const int row = m0 + wm + mt * 16 + quad * 4 + r;
        out[(size_t)row * 512 + col] = acc[mt][nt][r] + bcol;
      }
    }
  }
}

__global__ __launch_bounds__(256) void gemm_bt(
    const u16* __restrict__ A, const u16* __restrict__ W,
    const float* __restrict__ bias, float* __restrict__ out)
{
  __shared__ u16 As[128 * 32];
  __shared__ u16 Bs[128 * 32];
  gemm_body(A, W, bias, out, blockIdx.x * 128, blockIdx.y * 128, As, Bs);
}

__global__ __launch_bounds__(256) void gemm_bt4(
    const u16* __restrict__ A, const u16* __restrict__ Wbase,
    const float* __restrict__ b0, const float* __restrict__ b1,
    const float* __restrict__ b2, const float* __restrict__ b3,
    float* __restrict__ outbase)
{
  __shared__ u16 As[128 * 32];
  __shared__ u16 Bs[128 * 32];
  const int z = blockIdx.z;
  const u16* W = Wbase + (size_t)z * 512 * 512;
  const float* bias = (z == 0) ? b0 : (z == 1) ? b1 : (z == 2) ? b2 : b3;
  float* out = outbase + (size_t)z * ND_;
  gemm_body(A, W, bias, out, blockIdx.x * 128, blockIdx.y * 128, As, Bs);
}

// ---------------------------------------------------------------------------
// alpha/beta
// ---------------------------------------------------------------------------
__global__ __launch_bounds__(256) void ab_kernel(
    const float* __restrict__ x, const float* __restrict__ Wa, const float* __restrict__ ba,
    const float* __restrict__ Wb, const float* __restrict__ bb,
    float* __restrict__ alpha, float* __restrict__ beta)
{
  const int lane = threadIdx.x & 63, wave = threadIdx.x >> 6;
  const int row = blockIdx.x * 4 + wave;
  const float4 x0 = *(const float4*)(x + (size_t)row * 512 + lane * 8);
  const float4 x1 = *(const float4*)(x + (size_t)row * 512 + lane * 8 + 4);
  const float4 a0 = *(const float4*)(Wa + lane * 8);
  const float4 a1 = *(const float4*)(Wa + lane * 8 + 4);
  const float4 b0 = *(const float4*)(Wb + lane * 8);
  const float4 b1 = *(const float4*)(Wb + lane * 8 + 4);
  float da = x0.x*a0.x + x0.y*a0.y + x0.z*a0.z + x0.w*a0.w
           + x1.x*a1.x + x1.y*a1.y + x1.z*a1.z + x1.w*a1.w;
  float db = x0.x*b0.x + x0.y*b0.y + x0.z*b0.z + x0.w*b0.w
           + x1.x*b1.x + x1.y*b1.y + x1.z*b1.z + x1.w*b1.w;
#pragma unroll
  for (int m = 32; m >= 1; m >>= 1) { da += __shfl_xor(da, m, 64); db += __shfl_xor(db, m, 64); }
  if (lane == 0) {
    alpha[row] = sigm(da + ba[0]);
    beta[row]  = sigm(db + bb[0]);
  }
}

// ---------------------------------------------------------------------------
// causal depthwise conv (k=4) + SiLU (+ L2 norm for q,k -> bf16; v -> f32)
// ---------------------------------------------------------------------------
__global__ __launch_bounds__(256) void conv_act(
    const float* __restrict__ lq, const float* __restrict__ lk, const float* __restrict__ lv,
    const float* __restrict__ cwq, const float* __restrict__ cbq,
    const float* __restrict__ cwk, const float* __restrict__ cbk,
    const float* __restrict__ cwv, const float* __restrict__ cbv,
    u16* __restrict__ oq, u16* __restrict__ ok, float* __restrict__ ov)
{
  __shared__ float red[TB_][4];
  const int z = blockIdx.y;
  const int r0 = blockIdx.x * TB_;
  const int b = r0 / S_, t0 = r0 - b * S_;
  const float* lin = (z == 0) ? lq : (z == 1) ? lk : lv;
  const float* cw = (z == 0) ? cwq : (z == 1) ? cwk : cwv;
  const float* cb = (z == 0) ? cbq : (z == 1) ? cbk : cbv;
  const int tid = threadIdx.x;
  const int lane = tid & 63, wave = tid >> 6;

  float w4[2][4], bias[2];
#pragma unroll
  for (int e = 0; e < 2; e++) {
    const int ch = tid + e * 256;
    bias[e] = cb[ch];
#pragma unroll
    for (int tau = 0; tau < 4; tau++) w4[e][tau] = cw[ch * 4 + tau];
  }
  float win[2][TB_ + 3];
#pragma unroll
  for (int i = 0; i < TB_ + 3; i++) {
    const int tt = t0 - 3 + i;
#pragma unroll
    for (int e = 0; e < 2; e++)
      win[e][i] = (tt >= 0) ? lin[(size_t)(b * S_ + tt) * D_ + tid + e * 256] : 0.f;
  }
  float sv[2][TB_], ssq[TB_];
#pragma unroll
  for (int j = 0; j < TB_; j++) {
    float ss = 0.f;
#pragma unroll
    for (int e = 0; e < 2; e++) {
      float acc = bias[e];
#pragma unroll
      for (int tau = 0; tau < 4; tau++) acc = fmaf(win[e][j + tau], w4[e][tau], acc);
      const float s = acc * sigm(acc);
      sv[e][j] = s; ss = fmaf(s, s, ss);
    }
    ssq[j] = ss;
  }
  if (z < 2) {
#pragma unroll
    for (int j = 0; j < TB_; j++) {
#pragma unroll
      for (int m = 32; m >= 1; m >>= 1) ssq[j] += __shfl_xor(ssq[j], m, 64);
    }
    if (lane == 0) {
#pragma unroll
      for (int j = 0; j < TB_; j++) red[j][wave] = ssq[j];
    }
    __syncthreads();
    u16* outp = (z == 0) ? oq : ok;
#pragma unroll
    for (int j = 0; j < TB_; j++) {
      const float tot = red[j][0] + red[j][1] + red[j][2] + red[j][3];
      const float scale = 1.0f / fmaxf(sqrtf(tot), 1e-12f);
      outp[(size_t)(r0 + j) * D_ + tid] = f2bf(sv[0][j] * scale);
      outp[(size_t)(r0 + j) * D_ + tid + 256] = f2bf(sv[1][j] * scale);
    }
  } else {
#pragma unroll
    for (int j = 0; j < TB_; j++) {
      ov[(size_t)(r0 + j) * D_ + tid] = sv[0][j];
      ov[(size_t)(r0 + j) * D_ + tid + 256] = sv[1][j];
    }
  }
}

// ---------------------------------------------------------------------------
// transpose kh [b,t,ch] -> khT [b,ch,t]  (bf16), 64x64 tiles
// ---------------------------------------------------------------------------
__global__ __launch_bounds__(256) void transpose_k(
    const u16* __restrict__ kh, u16* __restrict__ khT)
{
  __shared__ u16 T[64][68];
  const int b = blockIdx.z;
  const int t0 = blockIdx.x * 64;
  const int c0 = blockIdx.y * 64;
  const int tid = threadIdx.x;
  const int tr = tid >> 4;
  const int c4 = (tid & 15) * 4;
#pragma unroll
  for (int i = 0; i < 4; i++) {
    const int t = tr + i * 16;
    ushort4 v = *(const ushort4*)(kh + ((size_t)(b * S_ + t0 + t)) * 512 + c0 + c4);
    T[c4 + 0][t] = v.x; T[c4 + 1][t] = v.y; T[c4 + 2][t] = v.z; T[c4 + 3][t] = v.w;
  }
  __syncthreads();
#pragma unroll
  for (int i = 0; i < 4; i++) {
    const int ch = tr + i * 16;
    ushort4 v = *(const ushort4*)&T[ch][c4];
    *(ushort4*)(khT + ((size_t)(b * 512 + c0 + ch)) * S_ + t0 + c4) = v;
  }
}

// ---------------------------------------------------------------------------
// prepass v2 (CC=64): per (b,chunk of 64):
//   KK = K K^T, QK = Q K^T (64x64 via MFMA), gamma tables, Ml, Ag;
//   X = (I+Ml)^-1 via block inverse: X11, X22 solved in PARALLEL (waves 0,1),
//   X21 = -X22*Ml21*X11 in f32 VALU; U = X*(betaV) in-place; Wc = X*beta*g*K.
// LDS overlay: VT (72KB) reuses the dead KK/QK/Ml/Xs/P21 pool.
// grid: 256 blocks (b*32+c), 256 threads, 1 block/CU.
// ---------------------------------------------------------------------------
__global__ __launch_bounds__(256) void prepass(
    const u16* __restrict__ kh, const u16* __restrict__ qh,
    float* __restrict__ vbU,              // in: betaless V (f32); out: U
    const float* __restrict__ alpha, const float* __restrict__ beta,
    u16* __restrict__ Ag, float* __restrict__ gg, u16* __restrict__ Wc)
{
  __shared__ __align__(16) char pool[73728];
  float (*KK)[65]  = (float (*)[65])(pool);
  float (*QK)[65]  = (float (*)[65])(pool + 16640);
  float (*Ml)[65]  = (float (*)[65])(pool + 33280);
  float (*Xs)[65]  = (float (*)[65])(pool + 49920);
  float (*P21)[33] = (float (*)[33])(pool + 66560);
  u16* VT = (u16*)pool;                 // 512*72 u16 = 73728 B (overlay)
  __shared__ u16 Xb[64 * 72];
  __shared__ float lg[64], cum[64], bet[64], gams[64];
  const int bc = blockIdx.x;
  const int b = bc >> 5, c = bc & 31;
  const int t0 = c * CC_;
  const int tid = threadIdx.x, lane = tid & 63, w = tid >> 6;
  const int l15 = lane & 15, quad = lane >> 4;
  const size_t rb = (size_t)b * S_ + t0;

  if (tid < 64) { lg[tid] = logf(alpha[rb + tid]); bet[tid] = beta[rb + tid]; }
  __syncthreads();
  if (tid < 64) {
    float s = 0.f;
    for (int u = 0; u <= tid; u++) s += lg[u];
    cum[tid] = s;
    gams[tid] = expf(s);
  }
  __syncthreads();
  if (tid < 64) {
    gg[(size_t)bc * 128 + tid] = gams[tid];
    gg[(size_t)bc * 128 + 64 + tid] = expf(cum[63] - cum[tid]);
  }
  // zero Xs (upper-right block must be 0; rest overwritten by solves)
#pragma unroll
  for (int rep = 0; rep < 17; rep++) {
    const int e = tid + rep * 256;
    if (e < 64 * 65) ((float*)Xs)[e] = 0.f;
  }
  // KK / QK: wave w owns m-tile w (rows w*16..+16), loops over 4 n-tiles
  for (int ni = 0; ni < 4; ni++) {
    f32x4 ck = (f32x4){0.f,0.f,0.f,0.f}, cq = ck;
#pragma unroll
    for (int kt = 0; kt < 16; kt++) {
      const int kc = kt * 32 + quad * 8;
      short8 afk = *(const short8*)(kh + (rb + w * 16 + l15) * 512 + kc);
      short8 afq = *(const short8*)(qh + (rb + w * 16 + l15) * 512 + kc);
      short8 bk  = *(const short8*)(kh + (rb + ni * 16 + l15) * 512 + kc);
      ck = __builtin_amdgcn_mfma_f32_16x16x32_bf16(afk, bk, ck, 0, 0, 0);
      cq = __builtin_amdgcn_mfma_f32_16x16x32_bf16(afq, bk, cq, 0, 0, 0);
    }
#pragma unroll
    for (int r = 0; r < 4; r++) {
      KK[w * 16 + quad * 4 + r][ni * 16 + l15] = ck[r];
      QK[w * 16 + quad * 4 + r][ni * 16 + l15] = cq[r];
    }
  }
  __syncthreads();
  // Ml and Ag
#pragma unroll
  for (int rep = 0; rep < 16; rep++) {
    const int e = tid + rep * 256;
    const int t = e >> 6, s = e & 63;
    const float er = expf(cum[t] - cum[s]);
    Ml[t][s] = (s < t) ? bet[t] * er * KK[t][s] : 0.f;
    Ag[(size_t)bc * 4096 + t * 64 + s] = (s <= t) ? f2bf(QK[t][s] * er) : (u16)0;
  }
  __syncthreads();
  // parallel 32x32 forward substitutions
  if (w == 0 && lane < 32) {
    const int j = lane;
    Xs[0][j] = (j == 0) ? 1.f : 0.f;
    for (int t = 1; t < 32; t++) {
      float a = (t == j) ? 1.f : 0.f;
      for (int u = 0; u < t; u++) a = fmaf(-Ml[t][u], Xs[u][j], a);
      Xs[t][j] = a;
    }
  }
  if (w == 1 && lane < 32) {
    const int j = lane;
    Xs[32][32 + j] = (j == 0) ? 1.f : 0.f;
    for (int t = 1; t < 32; t++) {
      float a = (t == j) ? 1.f : 0.f;
      for (int u = 0; u < t; u++) a = fmaf(-Ml[32 + t][32 + u], Xs[32 + u][32 + j], a);
      Xs[32 + t][32 + j] = a;
    }
  }
  __syncthreads();
  // P21 = Ml21 * X11 (f32)
#pragma unroll
  for (int rep = 0; rep < 4; rep++) {
    const int e = tid + rep * 256;
    const int i = e >> 5, j = e & 31;
    float a = 0.f;
    for (int u = 0; u < 32; u++) a = fmaf(Ml[32 + i][u], Xs[u][j], a);
    P21[i][j] = a;
  }
  __syncthreads();
  // X21 = -X22 * P21 (f32)
#pragma unroll
  for (int rep = 0; rep < 4; rep++) {
    const int e = tid + rep * 256;
    const int i = e >> 5, j = e & 31;
    float a = 0.f;
    for (int u = 0; u < 32; u++) a = fmaf(Xs[32 + i][32 + u], P21[u][j], a);
    Xs[32 + i][j] = -a;
  }
  __syncthreads();
  // Xb = bf16(X)
#pragma unroll
  for (int rep = 0; rep < 16; rep++) {
    const int e = tid + rep * 256;
    const int t = e >> 6, s = e & 63;
    Xb[t * 72 + s] = f2bf(Xs[t][s]);
  }
  __syncthreads();
  // VT = (beta V)^T  (overlay over KK/QK/Ml/Xs/P21 - all dead now)
#pragma unroll
  for (int rep = 0; rep < 16; rep++) {
    const int e = tid + rep * 256;
    const int v = e & 511, so = e >> 9;
    short8 pk;
#pragma unroll
    for (int j = 0; j < 8; j++) {
      const int s = so * 8 + j;
      pk[j] = (short)f2bf(bet[s] * vbU[(rb + s) * 512 + v]);
    }
    *(short8*)&VT[v * 72 + so * 8] = pk;
  }
  __syncthreads();
  // U = X * betaV (in place over vbU)
  short8 xa[4][2];
#pragma unroll
  for (int mt = 0; mt < 4; mt++)
#pragma unroll
    for (int ks = 0; ks < 2; ks++)
      xa[mt][ks] = *(const short8*)&Xb[(mt * 16 + l15) * 72 + ks * 32 + quad * 8];
#pragma unroll
  for (int ntr = 0; ntr < 8; ntr++) {
    const int nt = w * 8 + ntr;
    short8 bv0 = *(const short8*)&VT[(nt * 16 + l15) * 72 + quad * 8];
    short8 bv1 = *(const short8*)&VT[(nt * 16 + l15) * 72 + 32 + quad * 8];
#pragma unroll
    for (int mt = 0; mt < 4; mt++) {
      f32x4 g = (f32x4){0.f, 0.f, 0.f, 0.f};
      g = __builtin_amdgcn_mfma_f32_16x16x32_bf16(xa[mt][0], bv0, g, 0, 0, 0);
      g = __builtin_amdgcn_mfma_f32_16x16x32_bf16(xa[mt][1], bv1, g, 0, 0, 0);
#pragma unroll
      for (int r = 0; r < 4; r++)
        vbU[(rb + mt * 16 + quad * 4 + r) * 512 + nt * 16 + l15] = g[r];
    }
  }
  __syncthreads();
  // refill VT = (beta * gamma * K)^T
#pragma unroll
  for (int rep = 0; rep < 16; rep++) {
    const int e = tid + rep * 256;
    const int v = e & 511, so = e >> 9;
    short8 pk;
#pragma unroll
    for (int j = 0; j < 8; j++) {
      const int s = so * 8 + j;
      pk[j] = (short)f2bf(bet[s] * gams[s] * bf2f(kh[(rb + s) * 512 + v]));
    }
    *(short8*)&VT[v * 72 + so * 8] = pk;
  }
  __syncthreads();
  // Wc = X * beta*diag(gamma)*K  (bf16 out)
#pragma unroll
  for (int ntr = 0; ntr < 8; ntr++) {
    const int nt = w * 8 + ntr;
    short8 bv0 = *(const short8*)&VT[(nt * 16 + l15) * 72 + quad * 8];
    short8 bv1 = *(const short8*)&VT[(nt * 16 + l15) * 72 + 32 + quad * 8];
#pragma unroll
    for (int mt = 0; mt < 4; mt++) {
      f32x4 g = (f32x4){0.f, 0.f, 0.f, 0.f};
      g = __builtin_amdgcn_mfma_f32_16x16x32_bf16(xa[mt][0], bv0, g, 0, 0, 0);
      g = __builtin_amdgcn_mfma_f32_16x16x32_bf16(xa[mt][1], bv1, g, 0, 0, 0);
#pragma unroll
      for (int r = 0; r < 4; r++)
        Wc[((size_t)bc * 64 + mt * 16 + quad * 4 + r) * 512 + nt * 16 + l15] = f2bf(g[r]);
    }
  }
}

// ---------------------------------------------------------------------------
// chunked gated-delta scan v9 (CC=64): 512 thr (8 waves), SV_=16,
// grid (32,8)=256 blk, 32 iterations. Same 4-phase/3-barrier v4 skeleton,
// doubled per-iteration work to amortize the fixed ~6300cy/iter overhead.
// Wave task in phase B: (mat = w&1, ttile = w>>1), full K=512 (16 MFMAs).
// Loads for the CURRENT chunk issued at loop top (single-buffered, to stay
// under the 256-VGPR / 2-waves-per-SIMD cliff).
// ---------------------------------------------------------------------------
__global__ __launch_bounds__(512) void scan_chunk(
    const u16* __restrict__ qh, const u16* __restrict__ khT,
    const u16* __restrict__ Wc, const float* __restrict__ U,
    const u16* __restrict__ Ag, const float* __restrict__ gg,
    float* __restrict__ gdn)
{
  __shared__ u16 S_A[16 * 520];       // S[v][k] bf16
  __shared__ float P[2][64][20];      // [mat][t][v] (pad 20: aligned f32x4)
  __shared__ u16 Ct_T[16 * 72];       // C~^T [v][s]
  __shared__ u16 Cr_T[16 * 72];       // C~^T * (gC/gs)
  __shared__ float OB[64][17];        // gamma_t * T2 [t][v]
  __shared__ float gam[64], grc[64];
  const int b = blockIdx.y;
  const int iv0 = blockIdx.x * SV_;
  const int tid = threadIdx.x, lane = tid & 63, w = tid >> 6;
  const int l15 = lane & 15, quad = lane >> 4;
  const int mat = w & 1, ttile = w >> 1;
  const size_t bS = (size_t)b * S_;
  const int ct = tid >> 3, cvp = (tid & 7) * 2;   // phase-C coords (64 x 8x2)

  f32x4 acc[4];
#pragma unroll
  for (int mt = 0; mt < 4; mt++) acc[mt] = (f32x4){0.f, 0.f, 0.f, 0.f};

#pragma unroll 1
  for (int c = 0; c < NC_; c++) {
    const int t0 = c * CC_;
    const int bc = b * NC_ + c;
    // ---- loads for THIS chunk (drain at bar1 under phase A) ----
    short8 bfrag[16];
    const u16* bsrc = mat ? (qh + (bS + t0 + ttile * 16 + l15) * 512)
                          : (Wc + ((size_t)bc * 64 + ttile * 16 + l15) * 512);
#pragma unroll
    for (int kt = 0; kt < 16; kt++)
      bfrag[kt] = *(const short8*)(bsrc + kt * 32 + quad * 8);
    short8 tk[4][2];
#pragma unroll
    for (int mt = 0; mt < 4; mt++)
#pragma unroll
      for (int ks = 0; ks < 2; ks++)
        tk[mt][ks] = *(const short8*)(khT + ((size_t)(b * 512 + w * 64 + mt * 16 + l15)) * S_ + t0 + ks * 32 + quad * 8);
    float Uv[2];
#pragma unroll
    for (int e = 0; e < 2; e++)
      Uv[e] = U[(bS + t0 + ct) * 512 + iv0 + cvp + e];
    short8 agf[2];
    if (w < 4) {
#pragma unroll
      for (int ks = 0; ks < 2; ks++)
        agf[ks] = *(const short8*)(Ag + (size_t)bc * 4096 + (w * 16 + l15) * 64 + ks * 32 + quad * 8);
    }
    if (tid < 64) { gam[tid] = gg[(size_t)bc * 128 + tid]; grc[tid] = gg[(size_t)bc * 128 + 64 + tid]; }
    // ---- phase A: dump S to LDS ----
#pragma unroll
    for (int mt = 0; mt < 4; mt++) {
      ushort4 p;
      p.x = f2bf(acc[mt][0]); p.y = f2bf(acc[mt][1]);
      p.z = f2bf(acc[mt][2]); p.w = f2bf(acc[mt][3]);
      *(ushort4*)&S_A[l15 * 520 + w * 64 + mt * 16 + quad * 4] = p;
    }
    __syncthreads();
    // ---- phase B: one 16x16 P-tile per wave, full K=512 (16 MFMAs) ----
    f32x4 g0 = (f32x4){0.f, 0.f, 0.f, 0.f}, g1 = g0;
#pragma unroll
    for (int kt = 0; kt < 16; kt += 2) {
      short8 af0 = *(const short8*)&S_A[l15 * 520 + kt * 32 + quad * 8];
      short8 af1 = *(const short8*)&S_A[l15 * 520 + (kt + 1) * 32 + quad * 8];
      g0 = __builtin_amdgcn_mfma_f32_16x16x32_bf16(af0, bfrag[kt], g0, 0, 0, 0);
      g1 = __builtin_amdgcn_mfma_f32_16x16x32_bf16(af1, bfrag[kt + 1], g1, 0, 0, 0);
    }
    {
      f32x4 g = g0 + g1;
      *(f32x4*)&P[mat][ttile * 16 + l15][quad * 4] = g;
    }
    __syncthreads();
    // ---- phase C: C~ = U - T1, OB = gam*T2 (64t x 16v over 512 thr) ----
    const float gCs = gam[63];
#pragma unroll
    for (int e = 0; e < 2; e++) {
      const int cv = cvp + e;
      const float T1 = P[0][ct][cv];
      const float T2 = P[1][ct][cv];
      const float ctv = Uv[e] - T1;
      Ct_T[cv * 72 + ct] = f2bf(ctv);
      Cr_T[cv * 72 + ct] = f2bf(ctv * grc[ct]);
      OB[ct][cv] = gam[ct] * T2;
    }
    __syncthreads();
    // ---- phase F: state update (all waves); O GEMM (waves 0-3) -> gdn ----
    short8 bcf0 = *(const short8*)&Cr_T[l15 * 72 + quad * 8];
    short8 bcf1 = *(const short8*)&Cr_T[l15 * 72 + 32 + quad * 8];
#pragma unroll
    for (int mt = 0; mt < 4; mt++) {
      acc[mt] = acc[mt] * gCs;
      acc[mt] = __builtin_amdgcn_mfma_f32_16x16x32_bf16(tk[mt][0], bcf0, acc[mt], 0, 0, 0);
      acc[mt] = __builtin_amdgcn_mfma_f32_16x16x32_bf16(tk[mt][1], bcf1, acc[mt], 0, 0, 0);
    }
    if (w < 4) {
      short8 ctf0 = *(const short8*)&Ct_T[l15 * 72 + quad * 8];
      short8 ctf1 = *(const short8*)&Ct_T[l15 * 72 + 32 + quad * 8];
      f32x4 oo;
#pragma unroll
      for (int r = 0; r < 4; r++) oo[r] = OB[w * 16 + quad * 4 + r][l15];
      oo = __builtin_amdgcn_mfma_f32_16x16x32_bf16(agf[0], ctf0, oo, 0, 0, 0);
      oo = __builtin_amdgcn_mfma_f32_16x16x32_bf16(agf[1], ctf1, oo, 0, 0, 0);
#pragma unroll
      for (int r = 0; r < 4; r++)
        gdn[(bS + t0 + w * 16 + quad * 4 + r) * 512 + iv0 + l15] = oo[r];
    }
  }
}

// ---------------------------------------------------------------------------
// zero-centered rmsnorm * norm_w * silu(gate) -> bf16 h
// ---------------------------------------------------------------------------
__global__ __launch_bounds__(256) void norm_gate(
    const float* __restrict__ gdn, const float* __restrict__ lg,
    const float* __restrict__ nw, u16* __restrict__ h)
{
  __shared__ float red[8];
  const int row = blockIdx.x, tid = threadIdx.x;
  const size_t base = (size_t)row * D_;
  const float g0 = gdn[base + tid], g1 = gdn[base + tid + 256];
  float sm = g0 + g1;
#pragma unroll
  for (int m = 32; m >= 1; m >>= 1) sm += __shfl_xor(sm, m, 64);
  if ((tid & 63) == 0) red[tid >> 6] = sm;
  __syncthreads();
  const float mean = (red[0] + red[1] + red[2] + red[3]) * (1.0f / 512.0f);
  const float x0 = g0 - mean, x1 = g1 - mean;
  float sq = x0 * x0 + x1 * x1;
#pragma unroll
  for (int m = 32; m >= 1; m >>= 1) sq += __shfl_xor(sq, m, 64);
  if ((tid & 63) == 0) red[4 + (tid >> 6)] = sq;
  __syncthreads();
  const float var = (red[4] + red[5] + red[6] + red[7]) * (1.0f / 512.0f);
  const float rst = rsqrtf(var + 1e-5f);
  const float gl0 = lg[base + tid];
  h[base + tid] = f2bf(x0 * rst * nw[tid] * (gl0 * sigm(gl0)));
  const float gl1 = lg[base + tid + 256];
  h[base + tid + 256] = f2bf(x1 * rst * nw[tid + 256] * (gl1 * sigm(gl1)));
}

// ---------------------------------------------------------------------------
extern "C" void kernel_launch(void* const* d_in, const int* in_sizes, int n_in,
                              void* d_out, int out_size, void* d_ws, size_t ws_size,
                              hipStream_t stream)
{
  const float* x   = (const float*)d_in[0];
  const float* Wq  = (const float*)d_in[1];
  const float* bq  = (const float*)d_in[2];
  const float* Wk  = (const float*)d_in[3];
  const float* bk  = (const float*)d_in[4];
  const float* Wv  = (const float*)d_in[5];
  const float* bv  = (const float*)d_in[6];
  const float* Wa  = (const float*)d_in[7];
  const float* ba  = (const float*)d_in[8];
  const float* Wb  = (const float*)d_in[9];
  const float* bb  = (const float*)d_in[10];
  const float* cwq = (const float*)d_in[11];
  const float* cbq = (const float*)d_in[12];
  const float* cwk = (const float*)d_in[13];
  const float* cbk = (const float*)d_in[14];
  const float* cwv = (const float*)d_in[15];
  const float* cbv = (const float*)d_in[16];
  const float* nw  = (const float*)d_in[17];
  const float* Wg  = (const float*)d_in[18];
  const float* bg  = (const float*)d_in[19];
  const float* Wo  = (const float*)d_in[20];
  const float* bo  = (const float*)d_in[21];

  float* ws    = (float*)d_ws;
  float* lin_q = ws;               // f32; reused as gdn after conv
  float* lin_k = ws + ND_;         // f32; reused as khT/Ag/gg after conv
  float* lin_v = ws + 2 * ND_;     // f32; reused as Wc (prepass), then h
  float* lin_g = ws + 3 * ND_;
  float* vb    = ws + 4 * ND_;     // f32 v; overwritten IN PLACE by U in prepass
  u16*   qh    = (u16*)(ws + 5 * ND_);   // ND_ u16
  u16*   kh    = qh + ND_;               // ND_ u16
  float* alpha = ws + 6 * ND_;
  float* beta  = alpha + N_;
  u16*   xb    = (u16*)(beta + N_);
  u16*   wq_b  = xb + ND_;
  u16*   wk_b  = wq_b + 512 * 512;
  u16*   wv_b  = wk_b + 512 * 512;
  u16*   wg_b  = wv_b + 512 * 512;
  u16*   wo_b  = wg_b + 512 * 512;

  u16*   khT   = (u16*)lin_k;            // ND_ u16 (16MB)
  u16*   Agb   = khT + ND_;              // 256*4096 u16 (2MB)
  float* ggb   = (float*)(Agb + (size_t)256 * 4096);  // 256*128 f32
  u16*   Wcb   = (u16*)lin_v;            // 256*64*512 u16 (16MB)
  float* gdn   = lin_q;
  u16*   h     = (u16*)lin_v;            // written after Wc consumed

  const int NW = 512 * 512;
  cvt_bf16<<<(int)(ND_ / 1024), 256, 0, stream>>>(x, xb, (int)ND_);
  cvt_w5<<<dim3(NW / 1024, 5), 256, 0, stream>>>(Wq, Wk, Wv, Wg, Wo, wq_b);

  // fused Q/K/V/G input GEMMs: one launch, 2048 blocks (8/CU)
  gemm_bt4<<<dim3(128, 4, 4), 256, 0, stream>>>(xb, wq_b, bq, bk, bv, bg, ws);
  ab_kernel<<<N_ / 4, 256, 0, stream>>>(x, Wa, ba, Wb, bb, alpha, beta);
  conv_act<<<dim3(N_ / TB_, 3), 256, 0, stream>>>(lin_q, lin_k, lin_v,
                                                  cwq, cbq, cwk, cbk, cwv, cbv, qh, kh, vb);
  transpose_k<<<dim3(S_ / 64, D_ / 64, B_), 256, 0, stream>>>(kh, khT);
  prepass<<<B_ * NC_, 256, 0, stream>>>(kh, qh, vb, alpha, beta, Agb, ggb, Wcb);
  scan_chunk<<<dim3(D_ / SV_, B_), 512, 0, stream>>>(qh, khT, Wcb, vb, Agb, ggb, gdn);
  norm_gate<<<N_, 256, 0, stream>>>(gdn, lin_g, nw, h);
  gemm_bt<<<dim3(128, 4), 256, 0, stream>>>(h, wo_b, bo, (float*)d_out);
}

// Round 13
// 476.631 us; speedup vs baseline: 1.0785x; 1.0785x over previous
//
#include <hip/hip_runtime.h>
#include <math.h>

typedef unsigned short u16;
typedef unsigned int u32;
typedef short short8 __attribute__((ext_vector_type(8)));
typedef float f32x4 __attribute__((ext_vector_type(4)));

#define B_ 8
#define S_ 2048
#define D_ 512
#define N_ (B_ * S_)
#define ND_ ((size_t)N_ * D_)
#define CC_ 32              // chunk length (champion config)
#define NC_ (S_ / CC_)      // 64 chunks
#define SV_ 16              // v-rows per scan block
#define TB_ 8               // conv rows per block

__device__ __forceinline__ u16 f2bf(float f) {
  union { float f; u32 i; } v; v.f = f;
  u32 i = v.i;
  i += 0x7FFFu + ((i >> 16) & 1u);   // round-to-nearest-even
  return (u16)(i >> 16);
}
__device__ __forceinline__ float bf2f(u16 u) {
  union { u32 i; float f; } v; v.i = ((u32)u) << 16; return v.f;
}
__device__ __forceinline__ float sigm(float x) { return 1.0f / (1.0f + expf(-x)); }

__device__ __forceinline__ void glds16(const u16* g, u16* l) {
  __builtin_amdgcn_global_load_lds(
      (const __attribute__((address_space(1))) void*)g,
      (__attribute__((address_space(3))) void*)l, 16, 0, 0);
}

// ---------------------------------------------------------------------------
// f32 -> bf16 conversion (bulk, for x)
// ---------------------------------------------------------------------------
__global__ __launch_bounds__(256) void cvt_bf16(const float* __restrict__ s,
                                                u16* __restrict__ d, int n)
{
  const int i = (blockIdx.x * 256 + threadIdx.x) * 4;
  if (i < n) {
    const float4 v = *(const float4*)(s + i);
    ushort4 o;
    o.x = f2bf(v.x); o.y = f2bf(v.y); o.z = f2bf(v.z); o.w = f2bf(v.w);
    *(ushort4*)(d + i) = o;
  }
}

// ---------------------------------------------------------------------------
// fused f32 -> bf16 for the five 512x512 weight matrices (contiguous dst)
// ---------------------------------------------------------------------------
__global__ __launch_bounds__(256) void cvt_w5(
    const float* __restrict__ w0, const float* __restrict__ w1,
    const float* __restrict__ w2, const float* __restrict__ w3,
    const float* __restrict__ w4, u16* __restrict__ d)
{
  const int z = blockIdx.y;
  const float* s = (z == 0) ? w0 : (z == 1) ? w1 : (z == 2) ? w2 : (z == 3) ? w3 : w4;
  u16* o = d + (size_t)z * 512 * 512;
  const int i = (blockIdx.x * 256 + threadIdx.x) * 4;
  const float4 v = *(const float4*)(s + i);
  ushort4 t;
  t.x = f2bf(v.x); t.y = f2bf(v.y); t.z = f2bf(v.z); t.w = f2bf(v.w);
  *(ushort4*)(o + i) = t;
}

// ---------------------------------------------------------------------------
// GEMM core: 128x128 tile; staging via global_load_lds width=16 with k-slot
// XOR swizzle pre-applied to the global source (round-10 champion).
// ---------------------------------------------------------------------------
__device__ __forceinline__ void gemm_body(
    const u16* __restrict__ A, const u16* __restrict__ W,
    const float* __restrict__ bias, float* __restrict__ out,
    int m0, int n0, u16* As, u16* Bs)
{
  const int tid = threadIdx.x;
  const int lane = tid & 63, wave = tid >> 6;
  const int wm = (wave >> 1) * 64, wn = (wave & 1) * 64;
  const int l15 = lane & 15, quad = lane >> 4;

  const int lr = tid >> 2;
  const int ks = (tid & 3) ^ ((tid >> 3) & 3);
  u16* abase0 = As + wave * 512;
  u16* abase1 = As + 2048 + wave * 512;
  u16* bbase0 = Bs + wave * 512;
  u16* bbase1 = Bs + 2048 + wave * 512;

  f32x4 acc[4][4];
#pragma unroll
  for (int i = 0; i < 4; i++)
#pragma unroll
    for (int j = 0; j < 4; j++) acc[i][j] = (f32x4){0.f, 0.f, 0.f, 0.f};

  for (int k0 = 0; k0 < 512; k0 += 32) {
    __syncthreads();
    glds16(A + (size_t)(m0 + lr) * 512 + k0 + ks * 8, abase0);
    glds16(A + (size_t)(m0 + 64 + lr) * 512 + k0 + ks * 8, abase1);
    glds16(W + (size_t)(n0 + lr) * 512 + k0 + ks * 8, bbase0);
    glds16(W + (size_t)(n0 + 64 + lr) * 512 + k0 + ks * 8, bbase1);
    __syncthreads();
    short8 af[4], bf[4];
#pragma unroll
    for (int mt = 0; mt < 4; mt++) {
      const int row = wm + mt * 16 + l15;
      af[mt] = *(const short8*)(As + row * 32 + ((quad ^ ((row >> 1) & 3)) * 8));
    }
#pragma unroll
    for (int nt = 0; nt < 4; nt++) {
      const int row = wn + nt * 16 + l15;
      bf[nt] = *(const short8*)(Bs + row * 32 + ((quad ^ ((row >> 1) & 3)) * 8));
    }
#pragma unroll
    for (int mt = 0; mt < 4; mt++)
#pragma unroll
      for (int nt = 0; nt < 4; nt++)
        acc[mt][nt] = __builtin_amdgcn_mfma_f32_16x16x32_bf16(af[mt], bf[nt], acc[mt][nt], 0, 0, 0);
  }
#pragma unroll
  for (int mt = 0; mt < 4; mt++) {
#pragma unroll
    for (int nt = 0; nt < 4; nt++) {
      const int col = n0 + wn + nt * 16 + l15;
      const float bcol = bias[col];
#pragma unroll
      for (int r = 0; r < 4; r++) {
        const int row = m0 + wm + mt * 16 + quad * 4 + r;
        out[(size_t)row * 512 + col] = acc[mt][nt][r] + bcol;
      }
    }
  }
}

__global__ __launch_bounds__(256) void gemm_bt(
    const u16* __restrict__ A, const u16* __restrict__ W,
    const float* __restrict__ bias, float* __restrict__ out)
{
  __shared__ u16 As[128 * 32];
  __shared__ u16 Bs[128 * 32];
  gemm_body(A, W, bias, out, blockIdx.x * 128, blockIdx.y * 128, As, Bs);
}

__global__ __launch_bounds__(256) void gemm_bt4(
    const u16* __restrict__ A, const u16* __restrict__ Wbase,
    const float* __restrict__ b0, const float* __restrict__ b1,
    const float* __restrict__ b2, const float* __restrict__ b3,
    float* __restrict__ outbase)
{
  __shared__ u16 As[128 * 32];
  __shared__ u16 Bs[128 * 32];
  const int z = blockIdx.z;
  const u16* W = Wbase + (size_t)z * 512 * 512;
  const float* bias = (z == 0) ? b0 : (z == 1) ? b1 : (z == 2) ? b2 : b3;
  float* out = outbase + (size_t)z * ND_;
  gemm_body(A, W, bias, out, blockIdx.x * 128, blockIdx.y * 128, As, Bs);
}

// ---------------------------------------------------------------------------
// alpha/beta
// ---------------------------------------------------------------------------
__global__ __launch_bounds__(256) void ab_kernel(
    const float* __restrict__ x, const float* __restrict__ Wa, const float* __restrict__ ba,
    const float* __restrict__ Wb, const float* __restrict__ bb,
    float* __restrict__ alpha, float* __restrict__ beta)
{
  const int lane = threadIdx.x & 63, wave = threadIdx.x >> 6;
  const int row = blockIdx.x * 4 + wave;
  const float4 x0 = *(const float4*)(x + (size_t)row * 512 + lane * 8);
  const float4 x1 = *(const float4*)(x + (size_t)row * 512 + lane * 8 + 4);
  const float4 a0 = *(const float4*)(Wa + lane * 8);
  const float4 a1 = *(const float4*)(Wa + lane * 8 + 4);
  const float4 b0 = *(const float4*)(Wb + lane * 8);
  const float4 b1 = *(const float4*)(Wb + lane * 8 + 4);
  float da = x0.x*a0.x + x0.y*a0.y + x0.z*a0.z + x0.w*a0.w
           + x1.x*a1.x + x1.y*a1.y + x1.z*a1.z + x1.w*a1.w;
  float db = x0.x*b0.x + x0.y*b0.y + x0.z*b0.z + x0.w*b0.w
           + x1.x*b1.x + x1.y*b1.y + x1.z*b1.z + x1.w*b1.w;
#pragma unroll
  for (int m = 32; m >= 1; m >>= 1) { da += __shfl_xor(da, m, 64); db += __shfl_xor(db, m, 64); }
  if (lane == 0) {
    alpha[row] = sigm(da + ba[0]);
    beta[row]  = sigm(db + bb[0]);
  }
}

// ---------------------------------------------------------------------------
// causal depthwise conv (k=4) + SiLU (+ L2 norm for q,k -> bf16; v -> f32)
// ---------------------------------------------------------------------------
__global__ __launch_bounds__(256) void conv_act(
    const float* __restrict__ lq, const float* __restrict__ lk, const float* __restrict__ lv,
    const float* __restrict__ cwq, const float* __restrict__ cbq,
    const float* __restrict__ cwk, const float* __restrict__ cbk,
    const float* __restrict__ cwv, const float* __restrict__ cbv,
    u16* __restrict__ oq, u16* __restrict__ ok, float* __restrict__ ov)
{
  __shared__ float red[TB_][4];
  const int z = blockIdx.y;
  const int r0 = blockIdx.x * TB_;
  const int b = r0 / S_, t0 = r0 - b * S_;
  const float* lin = (z == 0) ? lq : (z == 1) ? lk : lv;
  const float* cw = (z == 0) ? cwq : (z == 1) ? cwk : cwv;
  const float* cb = (z == 0) ? cbq : (z == 1) ? cbk : cbv;
  const int tid = threadIdx.x;
  const int lane = tid & 63, wave = tid >> 6;

  float w4[2][4], bias[2];
#pragma unroll
  for (int e = 0; e < 2; e++) {
    const int ch = tid + e * 256;
    bias[e] = cb[ch];
#pragma unroll
    for (int tau = 0; tau < 4; tau++) w4[e][tau] = cw[ch * 4 + tau];
  }
  float win[2][TB_ + 3];
#pragma unroll
  for (int i = 0; i < TB_ + 3; i++) {
    const int tt = t0 - 3 + i;
#pragma unroll
    for (int e = 0; e < 2; e++)
      win[e][i] = (tt >= 0) ? lin[(size_t)(b * S_ + tt) * D_ + tid + e * 256] : 0.f;
  }
  float sv[2][TB_], ssq[TB_];
#pragma unroll
  for (int j = 0; j < TB_; j++) {
    float ss = 0.f;
#pragma unroll
    for (int e = 0; e < 2; e++) {
      float acc = bias[e];
#pragma unroll
      for (int tau = 0; tau < 4; tau++) acc = fmaf(win[e][j + tau], w4[e][tau], acc);
      const float s = acc * sigm(acc);
      sv[e][j] = s; ss = fmaf(s, s, ss);
    }
    ssq[j] = ss;
  }
  if (z < 2) {
#pragma unroll
    for (int j = 0; j < TB_; j++) {
#pragma unroll
      for (int m = 32; m >= 1; m >>= 1) ssq[j] += __shfl_xor(ssq[j], m, 64);
    }
    if (lane == 0) {
#pragma unroll
      for (int j = 0; j < TB_; j++) red[j][wave] = ssq[j];
    }
    __syncthreads();
    u16* outp = (z == 0) ? oq : ok;
#pragma unroll
    for (int j = 0; j < TB_; j++) {
      const float tot = red[j][0] + red[j][1] + red[j][2] + red[j][3];
      const float scale = 1.0f / fmaxf(sqrtf(tot), 1e-12f);
      outp[(size_t)(r0 + j) * D_ + tid] = f2bf(sv[0][j] * scale);
      outp[(size_t)(r0 + j) * D_ + tid + 256] = f2bf(sv[1][j] * scale);
    }
  } else {
#pragma unroll
    for (int j = 0; j < TB_; j++) {
      ov[(size_t)(r0 + j) * D_ + tid] = sv[0][j];
      ov[(size_t)(r0 + j) * D_ + tid + 256] = sv[1][j];
    }
  }
}

// ---------------------------------------------------------------------------
// transpose kh [b,t,ch] -> khT [b,ch,t]  (bf16), 64x64 tiles
// ---------------------------------------------------------------------------
__global__ __launch_bounds__(256) void transpose_k(
    const u16* __restrict__ kh, u16* __restrict__ khT)
{
  __shared__ u16 T[64][68];
  const int b = blockIdx.z;
  const int t0 = blockIdx.x * 64;
  const int c0 = blockIdx.y * 64;
  const int tid = threadIdx.x;
  const int tr = tid >> 4;
  const int c4 = (tid & 15) * 4;
#pragma unroll
  for (int i = 0; i < 4; i++) {
    const int t = tr + i * 16;
    ushort4 v = *(const ushort4*)(kh + ((size_t)(b * S_ + t0 + t)) * 512 + c0 + c4);
    T[c4 + 0][t] = v.x; T[c4 + 1][t] = v.y; T[c4 + 2][t] = v.z; T[c4 + 3][t] = v.w;
  }
  __syncthreads();
#pragma unroll
  for (int i = 0; i < 4; i++) {
    const int ch = tr + i * 16;
    ushort4 v = *(const ushort4*)&T[ch][c4];
    *(ushort4*)(khT + ((size_t)(b * 512 + c0 + ch)) * S_ + t0 + c4) = v;
  }
}

// ---------------------------------------------------------------------------
// prepass (CC=32 champion version)
// ---------------------------------------------------------------------------
__global__ __launch_bounds__(256) void prepass(
    const u16* __restrict__ kh, const u16* __restrict__ qh,
    float* __restrict__ vbU,              // in: betaless V (f32); out: U
    const float* __restrict__ alpha, const float* __restrict__ beta,
    u16* __restrict__ Ag, float* __restrict__ gg, u16* __restrict__ Wc)
{
  __shared__ float KK[32][33];
  __shared__ float QK[32][33];
  __shared__ float Ml[32][33];
  __shared__ float Xs[32][33];
  __shared__ u16 Xb[32 * 40];
  __shared__ u16 VT[512 * 40];           // transposed operand [col][s]
  __shared__ float lg[32], cum[32], bet[32], gams[32];
  const int bc = blockIdx.x;
  const int b = bc >> 6, c = bc & 63;
  const int t0 = c * CC_;
  const int tid = threadIdx.x, lane = tid & 63, w = tid >> 6;
  const int l15 = lane & 15, quad = lane >> 4;
  const size_t rb = (size_t)b * S_ + t0;

  if (tid < 32) { lg[tid] = logf(alpha[b * S_ + t0 + tid]); bet[tid] = beta[b * S_ + t0 + tid]; }
  __syncthreads();
  if (tid < 32) {
    float s = 0.f;
    for (int u = 0; u <= tid; u++) s += lg[u];
    cum[tid] = s;
    gams[tid] = expf(s);
  }
  // KK^T and QK^T quadrants
  const int mi = w >> 1, ni = w & 1;
  f32x4 ck = (f32x4){0.f,0.f,0.f,0.f}, cq = ck;
#pragma unroll
  for (int kt = 0; kt < 16; kt++) {
    const int kc = kt * 32 + quad * 8;
    short8 afk = *(const short8*)(kh + (rb + mi * 16 + l15) * 512 + kc);
    short8 afq = *(const short8*)(qh + (rb + mi * 16 + l15) * 512 + kc);
    short8 bk  = *(const short8*)(kh + (rb + ni * 16 + l15) * 512 + kc);
    ck = __builtin_amdgcn_mfma_f32_16x16x32_bf16(afk, bk, ck, 0, 0, 0);
    cq = __builtin_amdgcn_mfma_f32_16x16x32_bf16(afq, bk, cq, 0, 0, 0);
  }
#pragma unroll
  for (int r = 0; r < 4; r++) {
    KK[mi * 16 + quad * 4 + r][ni * 16 + l15] = ck[r];
    QK[mi * 16 + quad * 4 + r][ni * 16 + l15] = cq[r];
  }
  __syncthreads();
  if (tid < 32) {
    gg[(size_t)bc * 64 + tid] = gams[tid];
    gg[(size_t)bc * 64 + 32 + tid] = expf(cum[31] - cum[tid]);
  }
#pragma unroll
  for (int rep = 0; rep < 4; rep++) {
    const int e = tid + rep * 256;
    const int t = e >> 5, s = e & 31;
    const float er = expf(cum[t] - cum[s]);
    Ml[t][s] = (s < t) ? bet[t] * er * KK[t][s] : 0.f;
    Ag[(size_t)bc * 1024 + t * 32 + s] = (s <= t) ? f2bf(QK[t][s] * er) : (u16)0;
  }
  // stage V^T (beta-scaled, bf16) while the solve runs next
#pragma unroll
  for (int rep = 0; rep < 8; rep++) {
    const int e = tid + rep * 256;
    const int v = e & 511, so = e >> 9;
    short8 pk;
#pragma unroll
    for (int j = 0; j < 8; j++) {
      const int s = so * 8 + j;
      pk[j] = (short)f2bf(bet[s] * vbU[(rb + s) * 512 + v]);
    }
    *(short8*)&VT[v * 40 + so * 8] = pk;
  }
  __syncthreads();
  if (w == 0 && lane < 32) {
    const int j = lane;
    Xs[0][j] = (j == 0) ? 1.f : 0.f;
    for (int t = 1; t < 32; t++) {
      float a = (t == j) ? 1.f : 0.f;
      for (int u = 0; u < t; u++) a = fmaf(-Ml[t][u], Xs[u][j], a);
      Xs[t][j] = a;
    }
  }
  __syncthreads();
#pragma unroll
  for (int rep = 0; rep < 4; rep++) {
    const int e = tid + rep * 256;
    const int t = e >> 5, s = e & 31;
    Xb[t * 40 + s] = f2bf(Xs[t][s]);
  }
  __syncthreads();
  // U = X * betaV  (m=t 2 tiles, n = 512 v cols; wave w owns 8 n-tiles)
  short8 xa[2];
  xa[0] = *(const short8*)&Xb[l15 * 40 + quad * 8];
  xa[1] = *(const short8*)&Xb[(16 + l15) * 40 + quad * 8];
#pragma unroll
  for (int ntr = 0; ntr < 8; ntr++) {
    const int nt = w * 8 + ntr;
    short8 bv = *(const short8*)&VT[(nt * 16 + l15) * 40 + quad * 8];
#pragma unroll
    for (int mt = 0; mt < 2; mt++) {
      f32x4 g = (f32x4){0.f, 0.f, 0.f, 0.f};
      g = __builtin_amdgcn_mfma_f32_16x16x32_bf16(xa[mt], bv, g, 0, 0, 0);
#pragma unroll
      for (int r = 0; r < 4; r++)
        vbU[(rb + mt * 16 + quad * 4 + r) * 512 + nt * 16 + l15] = g[r];
    }
  }
  __syncthreads();
  // refill: K^T scaled by beta*gamma (bf16)
#pragma unroll
  for (int rep = 0; rep < 8; rep++) {
    const int e = tid + rep * 256;
    const int v = e & 511, so = e >> 9;
    short8 pk;
#pragma unroll
    for (int j = 0; j < 8; j++) {
      const int s = so * 8 + j;
      pk[j] = (short)f2bf(bet[s] * gams[s] * bf2f(kh[(rb + s) * 512 + v]));
    }
    *(short8*)&VT[v * 40 + so * 8] = pk;
  }
  __syncthreads();
  // Wc = X * beta*diag(gamma)*K  (bf16 out)
#pragma unroll
  for (int ntr = 0; ntr < 8; ntr++) {
    const int nt = w * 8 + ntr;
    short8 bv = *(const short8*)&VT[(nt * 16 + l15) * 40 + quad * 8];
#pragma unroll
    for (int mt = 0; mt < 2; mt++) {
      f32x4 g = (f32x4){0.f, 0.f, 0.f, 0.f};
      g = __builtin_amdgcn_mfma_f32_16x16x32_bf16(xa[mt], bv, g, 0, 0, 0);
#pragma unroll
      for (int r = 0; r < 4; r++)
        Wc[(size_t)bc * 16384 + (mt * 16 + quad * 4 + r) * 512 + nt * 16 + l15] = f2bf(g[r]);
    }
  }
}

// ---------------------------------------------------------------------------
// chunked gated-delta scan v4x (CC=32 champion + XCD-locality remap):
// 1D grid of 256 blocks; b = blockIdx.x & 7 so that (with round-robin
// workgroup->XCD dispatch) all 32 blocks sharing batch b land on ONE XCD.
// Their per-iteration streams of Wc/qh/khT/Ag/gg are identical, so the
// shared data is fetched into exactly one L2 instead of replicated into 8,
// cutting the drain latency on the serial critical path. Math unchanged.
// (Round-12 resubmission: round-11 bench was an infra failure, no data.)
// ---------------------------------------------------------------------------
__global__ __launch_bounds__(512) void scan_chunk(
    const u16* __restrict__ qh, const u16* __restrict__ khT,
    const u16* __restrict__ Wc, const float* __restrict__ U,
    const u16* __restrict__ Ag, const float* __restrict__ gg,
    float* __restrict__ gdn)
{
  __shared__ u16 S_A[16 * 520];       // S[v][k] bf16
  __shared__ float P[2][2][32][16];   // [mat][khalf][t][v]
  __shared__ u16 Ct_T[16 * 40];       // C~^T [v][s]
  __shared__ u16 Cr_T[16 * 40];       // C~^T * (gC/gs)
  __shared__ float OB[32][17];        // gamma_t * T2 [t][v]
  __shared__ float gam[32], grc[32];
  const int b = blockIdx.x & 7;                 // XCD-local batch
  const int iv0 = (blockIdx.x >> 3) * SV_;
  const int tid = threadIdx.x, lane = tid & 63, w = tid >> 6;
  const int l15 = lane & 15, quad = lane >> 4;
  const int ttile = w & 1, mat = (w >> 1) & 1, khalf = w >> 2;
  const size_t bS = (size_t)b * S_;
  const int ct = tid >> 4, cv = tid & 15;     // phase-C coords (32x16)

  f32x4 acc[4];
#pragma unroll
  for (int mt = 0; mt < 4; mt++) acc[mt] = (f32x4){0.f, 0.f, 0.f, 0.f};

  // prefetch registers (next chunk)
  short8 nbf[8], ntk[4], nagf = {};
  float nUv = 0.f, ngam = 0.f, ngrc = 0.f;

#define SCAN_LOAD(CN) do {                                                          \
    const int t0n_ = (CN) * CC_;                                                    \
    const int bcn_ = b * 64 + (CN);                                                 \
    const u16* bsrc_ = mat ? (qh + (bS + t0n_ + ttile * 16 + l15) * 512 + khalf * 256) \
                           : (Wc + ((size_t)bcn_ * 32 + ttile * 16 + l15) * 512 + khalf * 256); \
    _Pragma("unroll")                                                               \
    for (int kt_ = 0; kt_ < 8; kt_++)                                               \
      nbf[kt_] = *(const short8*)(bsrc_ + kt_ * 32 + quad * 8);                     \
    _Pragma("unroll")                                                               \
    for (int mt_ = 0; mt_ < 4; mt_++)                                               \
      ntk[mt_] = *(const short8*)(khT + ((size_t)(b * 512 + w * 64 + mt_ * 16 + l15)) * S_ + t0n_ + quad * 8); \
    nUv = U[(bS + t0n_ + ct) * 512 + iv0 + cv];                                     \
    if (w < 2) nagf = *(const short8*)(Ag + (size_t)bcn_ * 1024 + (w * 16 + l15) * 32 + quad * 8); \
    if (tid < 32) { ngam = gg[(size_t)bcn_ * 64 + tid]; ngrc = gg[(size_t)bcn_ * 64 + 32 + tid]; } \
  } while (0)

  SCAN_LOAD(0);

#pragma unroll 1
  for (int c = 0; c < NC_; c++) {
    const int t0 = c * CC_;
    // ---- rotate prefetched regs into current (waitcnt lands here) ----
    short8 bfrag[8], tk[4], agf;
#pragma unroll
    for (int kt = 0; kt < 8; kt++) bfrag[kt] = nbf[kt];
#pragma unroll
    for (int mt = 0; mt < 4; mt++) tk[mt] = ntk[mt];
    agf = nagf;
    const float Uv = nUv, gamv = ngam, grcv = ngrc;
    // ---- issue NEXT chunk's loads; they drain under this iteration ----
    const int cn = (c + 1 < NC_) ? c + 1 : c;
    SCAN_LOAD(cn);
    // ---- phase A: dump S to LDS; stage gamma tables ----
    if (tid < 32) { gam[tid] = gamv; grc[tid] = grcv; }
#pragma unroll
    for (int mt = 0; mt < 4; mt++) {
      ushort4 p;
      p.x = f2bf(acc[mt][0]); p.y = f2bf(acc[mt][1]);
      p.z = f2bf(acc[mt][2]); p.w = f2bf(acc[mt][3]);
      *(ushort4*)&S_A[l15 * 520 + w * 64 + mt * 16 + quad * 4] = p;
    }
    __syncthreads();
    // ---- phase B: one MFMA task per wave (8 MFMAs over its k-half) ----
    f32x4 g = (f32x4){0.f, 0.f, 0.f, 0.f};
#pragma unroll
    for (int kt = 0; kt < 8; kt++) {
      short8 af = *(const short8*)&S_A[l15 * 520 + khalf * 256 + kt * 32 + quad * 8];
      g = __builtin_amdgcn_mfma_f32_16x16x32_bf16(af, bfrag[kt], g, 0, 0, 0);
    }
    *(f32x4*)&P[mat][khalf][ttile * 16 + l15][quad * 4] = g;
    __syncthreads();
    // ---- phase C: 2-way reduce, C~ = U - T1, OB = gam*T2 ----
    const float gCs = gam[31];
    {
      const float T1 = P[0][0][ct][cv] + P[0][1][ct][cv];
      const float T2 = P[1][0][ct][cv] + P[1][1][ct][cv];
      const float ctv = Uv - T1;
      Ct_T[cv * 40 + ct] = f2bf(ctv);
      Cr_T[cv * 40 + ct] = f2bf(ctv * grc[ct]);
      OB[ct][cv] = gam[ct] * T2;
    }
    __syncthreads();
    // ---- phase F: state update (all waves); O GEMM (waves 0,1) -> gdn ----
    short8 bcf = *(const short8*)&Cr_T[l15 * 40 + quad * 8];
#pragma unroll
    for (int mt = 0; mt < 4; mt++) {
      acc[mt] = acc[mt] * gCs;
      acc[mt] = __builtin_amdgcn_mfma_f32_16x16x32_bf16(tk[mt], bcf, acc[mt], 0, 0, 0);
    }
    if (w < 2) {
      short8 ctf = *(const short8*)&Ct_T[l15 * 40 + quad * 8];
      f32x4 oo;
#pragma unroll
      for (int r = 0; r < 4; r++) oo[r] = OB[w * 16 + quad * 4 + r][l15];
      oo = __builtin_amdgcn_mfma_f32_16x16x32_bf16(agf, ctf, oo, 0, 0, 0);
#pragma unroll
      for (int r = 0; r < 4; r++)
        gdn[(bS + t0 + w * 16 + quad * 4 + r) * 512 + iv0 + l15] = oo[r];
    }
  }
#undef SCAN_LOAD
}

// ---------------------------------------------------------------------------
// zero-centered rmsnorm * norm_w * silu(gate) -> bf16 h
// ---------------------------------------------------------------------------
__global__ __launch_bounds__(256) void norm_gate(
    const float* __restrict__ gdn, const float* __restrict__ lg,
    const float* __restrict__ nw, u16* __restrict__ h)
{
  __shared__ float red[8];
  const int row = blockIdx.x, tid = threadIdx.x;
  const size_t base = (size_t)row * D_;
  const float g0 = gdn[base + tid], g1 = gdn[base + tid + 256];
  float sm = g0 + g1;
#pragma unroll
  for (int m = 32; m >= 1; m >>= 1) sm += __shfl_xor(sm, m, 64);
  if ((tid & 63) == 0) red[tid >> 6] = sm;
  __syncthreads();
  const float mean = (red[0] + red[1] + red[2] + red[3]) * (1.0f / 512.0f);
  const float x0 = g0 - mean, x1 = g1 - mean;
  float sq = x0 * x0 + x1 * x1;
#pragma unroll
  for (int m = 32; m >= 1; m >>= 1) sq += __shfl_xor(sq, m, 64);
  if ((tid & 63) == 0) red[4 + (tid >> 6)] = sq;
  __syncthreads();
  const float var = (red[4] + red[5] + red[6] + red[7]) * (1.0f / 512.0f);
  const float rst = rsqrtf(var + 1e-5f);
  const float gl0 = lg[base + tid];
  h[base + tid] = f2bf(x0 * rst * nw[tid] * (gl0 * sigm(gl0)));
  const float gl1 = lg[base + tid + 256];
  h[base + tid + 256] = f2bf(x1 * rst * nw[tid + 256] * (gl1 * sigm(gl1)));
}

// ---------------------------------------------------------------------------
extern "C" void kernel_launch(void* const* d_in, const int* in_sizes, int n_in,
                              void* d_out, int out_size, void* d_ws, size_t ws_size,
                              hipStream_t stream)
{
  const float* x   = (const float*)d_in[0];
  const float* Wq  = (const float*)d_in[1];
  const float* bq  = (const float*)d_in[2];
  const float* Wk  = (const float*)d_in[3];
  const float* bk  = (const float*)d_in[4];
  const float* Wv  = (const float*)d_in[5];
  const float* bv  = (const float*)d_in[6];
  const float* Wa  = (const float*)d_in[7];
  const float* ba  = (const float*)d_in[8];
  const float* Wb  = (const float*)d_in[9];
  const float* bb  = (const float*)d_in[10];
  const float* cwq = (const float*)d_in[11];
  const float* cbq = (const float*)d_in[12];
  const float* cwk = (const float*)d_in[13];
  const float* cbk = (const float*)d_in[14];
  const float* cwv = (const float*)d_in[15];
  const float* cbv = (const float*)d_in[16];
  const float* nw  = (const float*)d_in[17];
  const float* Wg  = (const float*)d_in[18];
  const float* bg  = (const float*)d_in[19];
  const float* Wo  = (const float*)d_in[20];
  const float* bo  = (const float*)d_in[21];

  float* ws    = (float*)d_ws;
  float* lin_q = ws;               // f32; reused as gdn after conv
  float* lin_k = ws + ND_;         // f32; reused as khT/Ag/gg after conv
  float* lin_v = ws + 2 * ND_;     // f32; reused as Wc (prepass), then h
  float* lin_g = ws + 3 * ND_;
  float* vb    = ws + 4 * ND_;     // f32 v; overwritten IN PLACE by U in prepass
  u16*   qh    = (u16*)(ws + 5 * ND_);   // ND_ u16
  u16*   kh    = qh + ND_;               // ND_ u16
  float* alpha = ws + 6 * ND_;
  float* beta  = alpha + N_;
  u16*   xb    = (u16*)(beta + N_);
  u16*   wq_b  = xb + ND_;
  u16*   wk_b  = wq_b + 512 * 512;
  u16*   wv_b  = wk_b + 512 * 512;
  u16*   wg_b  = wv_b + 512 * 512;
  u16*   wo_b  = wg_b + 512 * 512;

  u16*   khT   = (u16*)lin_k;            // ND_ u16 (16MB)
  u16*   Agb   = khT + ND_;              // 512*1024 u16 (1MB)
  float* ggb   = (float*)(Agb + (size_t)512 * 1024);  // 512*64 f32
  u16*   Wcb   = (u16*)lin_v;            // 512*32*512 u16 (16MB)
  float* gdn   = lin_q;
  u16*   h     = (u16*)lin_v;            // written after Wc consumed

  const int NW = 512 * 512;
  cvt_bf16<<<(int)(ND_ / 1024), 256, 0, stream>>>(x, xb, (int)ND_);
  cvt_w5<<<dim3(NW / 1024, 5), 256, 0, stream>>>(Wq, Wk, Wv, Wg, Wo, wq_b);

  // fused Q/K/V/G input GEMMs: one launch, 2048 blocks (8/CU)
  gemm_bt4<<<dim3(128, 4, 4), 256, 0, stream>>>(xb, wq_b, bq, bk, bv, bg, ws);
  ab_kernel<<<N_ / 4, 256, 0, stream>>>(x, Wa, ba, Wb, bb, alpha, beta);
  conv_act<<<dim3(N_ / TB_, 3), 256, 0, stream>>>(lin_q, lin_k, lin_v,
                                                  cwq, cbq, cwk, cbk, cwv, cbv, qh, kh, vb);
  transpose_k<<<dim3(S_ / 64, D_ / 64, B_), 256, 0, stream>>>(kh, khT);
  prepass<<<B_ * NC_, 256, 0, stream>>>(kh, qh, vb, alpha, beta, Agb, ggb, Wcb);
  scan_chunk<<<256, 512, 0, stream>>>(qh, khT, Wcb, vb, Agb, ggb, gdn);
  norm_gate<<<N_, 256, 0, stream>>>(gdn, lin_g, nw, h);
  gemm_bt<<<dim3(128, 4), 256, 0, stream>>>(h, wo_b, bo, (float*)d_out);
}

// Round 14
// 475.826 us; speedup vs baseline: 1.0803x; 1.0017x over previous
//
#include <hip/hip_runtime.h>
#include <math.h>

typedef unsigned short u16;
typedef unsigned int u32;
typedef short short8 __attribute__((ext_vector_type(8)));
typedef float f32x4 __attribute__((ext_vector_type(4)));

#define B_ 8
#define S_ 2048
#define D_ 512
#define N_ (B_ * S_)
#define ND_ ((size_t)N_ * D_)
#define CC_ 32              // chunk length (champion config)
#define NC_ (S_ / CC_)      // 64 chunks
#define SV_ 16              // v-rows per scan block
#define TB_ 8               // conv rows per block

__device__ __forceinline__ u16 f2bf(float f) {
  union { float f; u32 i; } v; v.f = f;
  u32 i = v.i;
  i += 0x7FFFu + ((i >> 16) & 1u);   // round-to-nearest-even
  return (u16)(i >> 16);
}
__device__ __forceinline__ float bf2f(u16 u) {
  union { u32 i; float f; } v; v.i = ((u32)u) << 16; return v.f;
}
__device__ __forceinline__ float sigm(float x) { return 1.0f / (1.0f + expf(-x)); }

__device__ __forceinline__ void glds16(const u16* g, u16* l) {
  __builtin_amdgcn_global_load_lds(
      (const __attribute__((address_space(1))) void*)g,
      (__attribute__((address_space(3))) void*)l, 16, 0, 0);
}

// ---------------------------------------------------------------------------
// f32 -> bf16 conversion (bulk, for x)
// ---------------------------------------------------------------------------
__global__ __launch_bounds__(256) void cvt_bf16(const float* __restrict__ s,
                                                u16* __restrict__ d, int n)
{
  const int i = (blockIdx.x * 256 + threadIdx.x) * 4;
  if (i < n) {
    const float4 v = *(const float4*)(s + i);
    ushort4 o;
    o.x = f2bf(v.x); o.y = f2bf(v.y); o.z = f2bf(v.z); o.w = f2bf(v.w);
    *(ushort4*)(d + i) = o;
  }
}

// ---------------------------------------------------------------------------
// fused f32 -> bf16 for the five 512x512 weight matrices (contiguous dst)
// ---------------------------------------------------------------------------
__global__ __launch_bounds__(256) void cvt_w5(
    const float* __restrict__ w0, const float* __restrict__ w1,
    const float* __restrict__ w2, const float* __restrict__ w3,
    const float* __restrict__ w4, u16* __restrict__ d)
{
  const int z = blockIdx.y;
  const float* s = (z == 0) ? w0 : (z == 1) ? w1 : (z == 2) ? w2 : (z == 3) ? w3 : w4;
  u16* o = d + (size_t)z * 512 * 512;
  const int i = (blockIdx.x * 256 + threadIdx.x) * 4;
  const float4 v = *(const float4*)(s + i);
  ushort4 t;
  t.x = f2bf(v.x); t.y = f2bf(v.y); t.z = f2bf(v.z); t.w = f2bf(v.w);
  *(ushort4*)(o + i) = t;
}

// ---------------------------------------------------------------------------
// GEMM core: 128x128 tile; staging via global_load_lds width=16 with k-slot
// XOR swizzle pre-applied to the global source (round-10 champion).
// ---------------------------------------------------------------------------
__device__ __forceinline__ void gemm_body(
    const u16* __restrict__ A, const u16* __restrict__ W,
    const float* __restrict__ bias, float* __restrict__ out,
    int m0, int n0, u16* As, u16* Bs)
{
  const int tid = threadIdx.x;
  const int lane = tid & 63, wave = tid >> 6;
  const int wm = (wave >> 1) * 64, wn = (wave & 1) * 64;
  const int l15 = lane & 15, quad = lane >> 4;

  const int lr = tid >> 2;
  const int ks = (tid & 3) ^ ((tid >> 3) & 3);
  u16* abase0 = As + wave * 512;
  u16* abase1 = As + 2048 + wave * 512;
  u16* bbase0 = Bs + wave * 512;
  u16* bbase1 = Bs + 2048 + wave * 512;

  f32x4 acc[4][4];
#pragma unroll
  for (int i = 0; i < 4; i++)
#pragma unroll
    for (int j = 0; j < 4; j++) acc[i][j] = (f32x4){0.f, 0.f, 0.f, 0.f};

  for (int k0 = 0; k0 < 512; k0 += 32) {
    __syncthreads();
    glds16(A + (size_t)(m0 + lr) * 512 + k0 + ks * 8, abase0);
    glds16(A + (size_t)(m0 + 64 + lr) * 512 + k0 + ks * 8, abase1);
    glds16(W + (size_t)(n0 + lr) * 512 + k0 + ks * 8, bbase0);
    glds16(W + (size_t)(n0 + 64 + lr) * 512 + k0 + ks * 8, bbase1);
    __syncthreads();
    short8 af[4], bf[4];
#pragma unroll
    for (int mt = 0; mt < 4; mt++) {
      const int row = wm + mt * 16 + l15;
      af[mt] = *(const short8*)(As + row * 32 + ((quad ^ ((row >> 1) & 3)) * 8));
    }
#pragma unroll
    for (int nt = 0; nt < 4; nt++) {
      const int row = wn + nt * 16 + l15;
      bf[nt] = *(const short8*)(Bs + row * 32 + ((quad ^ ((row >> 1) & 3)) * 8));
    }
#pragma unroll
    for (int mt = 0; mt < 4; mt++)
#pragma unroll
      for (int nt = 0; nt < 4; nt++)
        acc[mt][nt] = __builtin_amdgcn_mfma_f32_16x16x32_bf16(af[mt], bf[nt], acc[mt][nt], 0, 0, 0);
  }
#pragma unroll
  for (int mt = 0; mt < 4; mt++) {
#pragma unroll
    for (int nt = 0; nt < 4; nt++) {
      const int col = n0 + wn + nt * 16 + l15;
      const float bcol = bias[col];
#pragma unroll
      for (int r = 0; r < 4; r++) {
        const int row = m0 + wm + mt * 16 + quad * 4 + r;
        out[(size_t)row * 512 + col] = acc[mt][nt][r] + bcol;
      }
    }
  }
}

__global__ __launch_bounds__(256) void gemm_bt(
    const u16* __restrict__ A, const u16* __restrict__ W,
    const float* __restrict__ bias, float* __restrict__ out)
{
  __shared__ u16 As[128 * 32];
  __shared__ u16 Bs[128 * 32];
  gemm_body(A, W, bias, out, blockIdx.x * 128, blockIdx.y * 128, As, Bs);
}

__global__ __launch_bounds__(256) void gemm_bt4(
    const u16* __restrict__ A, const u16* __restrict__ Wbase,
    const float* __restrict__ b0, const float* __restrict__ b1,
    const float* __restrict__ b2, const float* __restrict__ b3,
    float* __restrict__ outbase)
{
  __shared__ u16 As[128 * 32];
  __shared__ u16 Bs[128 * 32];
  const int z = blockIdx.z;
  const u16* W = Wbase + (size_t)z * 512 * 512;
  const float* bias = (z == 0) ? b0 : (z == 1) ? b1 : (z == 2) ? b2 : b3;
  float* out = outbase + (size_t)z * ND_;
  gemm_body(A, W, bias, out, blockIdx.x * 128, blockIdx.y * 128, As, Bs);
}

// ---------------------------------------------------------------------------
// alpha/beta
// ---------------------------------------------------------------------------
__global__ __launch_bounds__(256) void ab_kernel(
    const float* __restrict__ x, const float* __restrict__ Wa, const float* __restrict__ ba,
    const float* __restrict__ Wb, const float* __restrict__ bb,
    float* __restrict__ alpha, float* __restrict__ beta)
{
  const int lane = threadIdx.x & 63, wave = threadIdx.x >> 6;
  const int row = blockIdx.x * 4 + wave;
  const float4 x0 = *(const float4*)(x + (size_t)row * 512 + lane * 8);
  const float4 x1 = *(const float4*)(x + (size_t)row * 512 + lane * 8 + 4);
  const float4 a0 = *(const float4*)(Wa + lane * 8);
  const float4 a1 = *(const float4*)(Wa + lane * 8 + 4);
  const float4 b0 = *(const float4*)(Wb + lane * 8);
  const float4 b1 = *(const float4*)(Wb + lane * 8 + 4);
  float da = x0.x*a0.x + x0.y*a0.y + x0.z*a0.z + x0.w*a0.w
           + x1.x*a1.x + x1.y*a1.y + x1.z*a1.z + x1.w*a1.w;
  float db = x0.x*b0.x + x0.y*b0.y + x0.z*b0.z + x0.w*b0.w
           + x1.x*b1.x + x1.y*b1.y + x1.z*b1.z + x1.w*b1.w;
#pragma unroll
  for (int m = 32; m >= 1; m >>= 1) { da += __shfl_xor(da, m, 64); db += __shfl_xor(db, m, 64); }
  if (lane == 0) {
    alpha[row] = sigm(da + ba[0]);
    beta[row]  = sigm(db + bb[0]);
  }
}

// ---------------------------------------------------------------------------
// causal depthwise conv (k=4) + SiLU (+ L2 norm for q,k -> bf16; v -> f32)
// ---------------------------------------------------------------------------
__global__ __launch_bounds__(256) void conv_act(
    const float* __restrict__ lq, const float* __restrict__ lk, const float* __restrict__ lv,
    const float* __restrict__ cwq, const float* __restrict__ cbq,
    const float* __restrict__ cwk, const float* __restrict__ cbk,
    const float* __restrict__ cwv, const float* __restrict__ cbv,
    u16* __restrict__ oq, u16* __restrict__ ok, float* __restrict__ ov)
{
  __shared__ float red[TB_][4];
  const int z = blockIdx.y;
  const int r0 = blockIdx.x * TB_;
  const int b = r0 / S_, t0 = r0 - b * S_;
  const float* lin = (z == 0) ? lq : (z == 1) ? lk : lv;
  const float* cw = (z == 0) ? cwq : (z == 1) ? cwk : cwv;
  const float* cb = (z == 0) ? cbq : (z == 1) ? cbk : cbv;
  const int tid = threadIdx.x;
  const int lane = tid & 63, wave = tid >> 6;

  float w4[2][4], bias[2];
#pragma unroll
  for (int e = 0; e < 2; e++) {
    const int ch = tid + e * 256;
    bias[e] = cb[ch];
#pragma unroll
    for (int tau = 0; tau < 4; tau++) w4[e][tau] = cw[ch * 4 + tau];
  }
  float win[2][TB_ + 3];
#pragma unroll
  for (int i = 0; i < TB_ + 3; i++) {
    const int tt = t0 - 3 + i;
#pragma unroll
    for (int e = 0; e < 2; e++)
      win[e][i] = (tt >= 0) ? lin[(size_t)(b * S_ + tt) * D_ + tid + e * 256] : 0.f;
  }
  float sv[2][TB_], ssq[TB_];
#pragma unroll
  for (int j = 0; j < TB_; j++) {
    float ss = 0.f;
#pragma unroll
    for (int e = 0; e < 2; e++) {
      float acc = bias[e];
#pragma unroll
      for (int tau = 0; tau < 4; tau++) acc = fmaf(win[e][j + tau], w4[e][tau], acc);
      const float s = acc * sigm(acc);
      sv[e][j] = s; ss = fmaf(s, s, ss);
    }
    ssq[j] = ss;
  }
  if (z < 2) {
#pragma unroll
    for (int j = 0; j < TB_; j++) {
#pragma unroll
      for (int m = 32; m >= 1; m >>= 1) ssq[j] += __shfl_xor(ssq[j], m, 64);
    }
    if (lane == 0) {
#pragma unroll
      for (int j = 0; j < TB_; j++) red[j][wave] = ssq[j];
    }
    __syncthreads();
    u16* outp = (z == 0) ? oq : ok;
#pragma unroll
    for (int j = 0; j < TB_; j++) {
      const float tot = red[j][0] + red[j][1] + red[j][2] + red[j][3];
      const float scale = 1.0f / fmaxf(sqrtf(tot), 1e-12f);
      outp[(size_t)(r0 + j) * D_ + tid] = f2bf(sv[0][j] * scale);
      outp[(size_t)(r0 + j) * D_ + tid + 256] = f2bf(sv[1][j] * scale);
    }
  } else {
#pragma unroll
    for (int j = 0; j < TB_; j++) {
      ov[(size_t)(r0 + j) * D_ + tid] = sv[0][j];
      ov[(size_t)(r0 + j) * D_ + tid + 256] = sv[1][j];
    }
  }
}

// ---------------------------------------------------------------------------
// transpose kh [b,t,ch] -> khT [b,ch,t]  (bf16), 64x64 tiles
// ---------------------------------------------------------------------------
__global__ __launch_bounds__(256) void transpose_k(
    const u16* __restrict__ kh, u16* __restrict__ khT)
{
  __shared__ u16 T[64][68];
  const int b = blockIdx.z;
  const int t0 = blockIdx.x * 64;
  const int c0 = blockIdx.y * 64;
  const int tid = threadIdx.x;
  const int tr = tid >> 4;
  const int c4 = (tid & 15) * 4;
#pragma unroll
  for (int i = 0; i < 4; i++) {
    const int t = tr + i * 16;
    ushort4 v = *(const ushort4*)(kh + ((size_t)(b * S_ + t0 + t)) * 512 + c0 + c4);
    T[c4 + 0][t] = v.x; T[c4 + 1][t] = v.y; T[c4 + 2][t] = v.z; T[c4 + 3][t] = v.w;
  }
  __syncthreads();
#pragma unroll
  for (int i = 0; i < 4; i++) {
    const int ch = tr + i * 16;
    ushort4 v = *(const ushort4*)&T[ch][c4];
    *(ushort4*)(khT + ((size_t)(b * 512 + c0 + ch)) * S_ + t0 + c4) = v;
  }
}

// ---------------------------------------------------------------------------
// prepass (CC=32 champion version)
// ---------------------------------------------------------------------------
__global__ __launch_bounds__(256) void prepass(
    const u16* __restrict__ kh, const u16* __restrict__ qh,
    float* __restrict__ vbU,              // in: betaless V (f32); out: U
    const float* __restrict__ alpha, const float* __restrict__ beta,
    u16* __restrict__ Ag, float* __restrict__ gg, u16* __restrict__ Wc)
{
  __shared__ float KK[32][33];
  __shared__ float QK[32][33];
  __shared__ float Ml[32][33];
  __shared__ float Xs[32][33];
  __shared__ u16 Xb[32 * 40];
  __shared__ u16 VT[512 * 40];           // transposed operand [col][s]
  __shared__ float lg[32], cum[32], bet[32], gams[32];
  const int bc = blockIdx.x;
  const int b = bc >> 6, c = bc & 63;
  const int t0 = c * CC_;
  const int tid = threadIdx.x, lane = tid & 63, w = tid >> 6;
  const int l15 = lane & 15, quad = lane >> 4;
  const size_t rb = (size_t)b * S_ + t0;

  if (tid < 32) { lg[tid] = logf(alpha[b * S_ + t0 + tid]); bet[tid] = beta[b * S_ + t0 + tid]; }
  __syncthreads();
  if (tid < 32) {
    float s = 0.f;
    for (int u = 0; u <= tid; u++) s += lg[u];
    cum[tid] = s;
    gams[tid] = expf(s);
  }
  // KK^T and QK^T quadrants
  const int mi = w >> 1, ni = w & 1;
  f32x4 ck = (f32x4){0.f,0.f,0.f,0.f}, cq = ck;
#pragma unroll
  for (int kt = 0; kt < 16; kt++) {
    const int kc = kt * 32 + quad * 8;
    short8 afk = *(const short8*)(kh + (rb + mi * 16 + l15) * 512 + kc);
    short8 afq = *(const short8*)(qh + (rb + mi * 16 + l15) * 512 + kc);
    short8 bk  = *(const short8*)(kh + (rb + ni * 16 + l15) * 512 + kc);
    ck = __builtin_amdgcn_mfma_f32_16x16x32_bf16(afk, bk, ck, 0, 0, 0);
    cq = __builtin_amdgcn_mfma_f32_16x16x32_bf16(afq, bk, cq, 0, 0, 0);
  }
#pragma unroll
  for (int r = 0; r < 4; r++) {
    KK[mi * 16 + quad * 4 + r][ni * 16 + l15] = ck[r];
    QK[mi * 16 + quad * 4 + r][ni * 16 + l15] = cq[r];
  }
  __syncthreads();
  if (tid < 32) {
    gg[(size_t)bc * 64 + tid] = gams[tid];
    gg[(size_t)bc * 64 + 32 + tid] = expf(cum[31] - cum[tid]);
  }
#pragma unroll
  for (int rep = 0; rep < 4; rep++) {
    const int e = tid + rep * 256;
    const int t = e >> 5, s = e & 31;
    const float er = expf(cum[t] - cum[s]);
    Ml[t][s] = (s < t) ? bet[t] * er * KK[t][s] : 0.f;
    Ag[(size_t)bc * 1024 + t * 32 + s] = (s <= t) ? f2bf(QK[t][s] * er) : (u16)0;
  }
  // stage V^T (beta-scaled, bf16) while the solve runs next
#pragma unroll
  for (int rep = 0; rep < 8; rep++) {
    const int e = tid + rep * 256;
    const int v = e & 511, so = e >> 9;
    short8 pk;
#pragma unroll
    for (int j = 0; j < 8; j++) {
      const int s = so * 8 + j;
      pk[j] = (short)f2bf(bet[s] * vbU[(rb + s) * 512 + v]);
    }
    *(short8*)&VT[v * 40 + so * 8] = pk;
  }
  __syncthreads();
  if (w == 0 && lane < 32) {
    const int j = lane;
    Xs[0][j] = (j == 0) ? 1.f : 0.f;
    for (int t = 1; t < 32; t++) {
      float a = (t == j) ? 1.f : 0.f;
      for (int u = 0; u < t; u++) a = fmaf(-Ml[t][u], Xs[u][j], a);
      Xs[t][j] = a;
    }
  }
  __syncthreads();
#pragma unroll
  for (int rep = 0; rep < 4; rep++) {
    const int e = tid + rep * 256;
    const int t = e >> 5, s = e & 31;
    Xb[t * 40 + s] = f2bf(Xs[t][s]);
  }
  __syncthreads();
  // U = X * betaV  (m=t 2 tiles, n = 512 v cols; wave w owns 8 n-tiles)
  short8 xa[2];
  xa[0] = *(const short8*)&Xb[l15 * 40 + quad * 8];
  xa[1] = *(const short8*)&Xb[(16 + l15) * 40 + quad * 8];
#pragma unroll
  for (int ntr = 0; ntr < 8; ntr++) {
    const int nt = w * 8 + ntr;
    short8 bv = *(const short8*)&VT[(nt * 16 + l15) * 40 + quad * 8];
#pragma unroll
    for (int mt = 0; mt < 2; mt++) {
      f32x4 g = (f32x4){0.f, 0.f, 0.f, 0.f};
      g = __builtin_amdgcn_mfma_f32_16x16x32_bf16(xa[mt], bv, g, 0, 0, 0);
#pragma unroll
      for (int r = 0; r < 4; r++)
        vbU[(rb + mt * 16 + quad * 4 + r) * 512 + nt * 16 + l15] = g[r];
    }
  }
  __syncthreads();
  // refill: K^T scaled by beta*gamma (bf16)
#pragma unroll
  for (int rep = 0; rep < 8; rep++) {
    const int e = tid + rep * 256;
    const int v = e & 511, so = e >> 9;
    short8 pk;
#pragma unroll
    for (int j = 0; j < 8; j++) {
      const int s = so * 8 + j;
      pk[j] = (short)f2bf(bet[s] * gams[s] * bf2f(kh[(rb + s) * 512 + v]));
    }
    *(short8*)&VT[v * 40 + so * 8] = pk;
  }
  __syncthreads();
  // Wc = X * beta*diag(gamma)*K  (bf16 out)
#pragma unroll
  for (int ntr = 0; ntr < 8; ntr++) {
    const int nt = w * 8 + ntr;
    short8 bv = *(const short8*)&VT[(nt * 16 + l15) * 40 + quad * 8];
#pragma unroll
    for (int mt = 0; mt < 2; mt++) {
      f32x4 g = (f32x4){0.f, 0.f, 0.f, 0.f};
      g = __builtin_amdgcn_mfma_f32_16x16x32_bf16(xa[mt], bv, g, 0, 0, 0);
#pragma unroll
      for (int r = 0; r < 4; r++)
        Wc[(size_t)bc * 16384 + (mt * 16 + quad * 4 + r) * 512 + nt * 16 + l15] = f2bf(g[r]);
    }
  }
}

// ---------------------------------------------------------------------------
// chunked gated-delta scan v4x2 (champion + XCD remap + P stride 20):
// the P[.][.][32][16] f32x4 write was an 8-way bank conflict (banks {0,16}
// only: 16 f32 row stride) -- the source of the constant 1.11e7
// SQ_LDS_BANK_CONFLICT. Stride 20 (80B rows) keeps 16B alignment and
// spreads the quarter-wave across all 32 banks (2-way = free).
// ---------------------------------------------------------------------------
__global__ __launch_bounds__(512) void scan_chunk(
    const u16* __restrict__ qh, const u16* __restrict__ khT,
    const u16* __restrict__ Wc, const float* __restrict__ U,
    const u16* __restrict__ Ag, const float* __restrict__ gg,
    float* __restrict__ gdn)
{
  __shared__ u16 S_A[16 * 520];       // S[v][k] bf16
  __shared__ float P[2][2][32][20];   // [mat][khalf][t][v] (pad 20: aligned, conflict-free)
  __shared__ u16 Ct_T[16 * 40];       // C~^T [v][s]
  __shared__ u16 Cr_T[16 * 40];       // C~^T * (gC/gs)
  __shared__ float OB[32][17];        // gamma_t * T2 [t][v]
  __shared__ float gam[32], grc[32];
  const int b = blockIdx.x & 7;                 // XCD-local batch
  const int iv0 = (blockIdx.x >> 3) * SV_;
  const int tid = threadIdx.x, lane = tid & 63, w = tid >> 6;
  const int l15 = lane & 15, quad = lane >> 4;
  const int ttile = w & 1, mat = (w >> 1) & 1, khalf = w >> 2;
  const size_t bS = (size_t)b * S_;
  const int ct = tid >> 4, cv = tid & 15;     // phase-C coords (32x16)

  f32x4 acc[4];
#pragma unroll
  for (int mt = 0; mt < 4; mt++) acc[mt] = (f32x4){0.f, 0.f, 0.f, 0.f};

  // prefetch registers (next chunk)
  short8 nbf[8], ntk[4], nagf = {};
  float nUv = 0.f, ngam = 0.f, ngrc = 0.f;

#define SCAN_LOAD(CN) do {                                                          \
    const int t0n_ = (CN) * CC_;                                                    \
    const int bcn_ = b * 64 + (CN);                                                 \
    const u16* bsrc_ = mat ? (qh + (bS + t0n_ + ttile * 16 + l15) * 512 + khalf * 256) \
                           : (Wc + ((size_t)bcn_ * 32 + ttile * 16 + l15) * 512 + khalf * 256); \
    _Pragma("unroll")                                                               \
    for (int kt_ = 0; kt_ < 8; kt_++)                                               \
      nbf[kt_] = *(const short8*)(bsrc_ + kt_ * 32 + quad * 8);                     \
    _Pragma("unroll")                                                               \
    for (int mt_ = 0; mt_ < 4; mt_++)                                               \
      ntk[mt_] = *(const short8*)(khT + ((size_t)(b * 512 + w * 64 + mt_ * 16 + l15)) * S_ + t0n_ + quad * 8); \
    nUv = U[(bS + t0n_ + ct) * 512 + iv0 + cv];                                     \
    if (w < 2) nagf = *(const short8*)(Ag + (size_t)bcn_ * 1024 + (w * 16 + l15) * 32 + quad * 8); \
    if (tid < 32) { ngam = gg[(size_t)bcn_ * 64 + tid]; ngrc = gg[(size_t)bcn_ * 64 + 32 + tid]; } \
  } while (0)

  SCAN_LOAD(0);

#pragma unroll 1
  for (int c = 0; c < NC_; c++) {
    const int t0 = c * CC_;
    // ---- rotate prefetched regs into current (waitcnt lands here) ----
    short8 bfrag[8], tk[4], agf;
#pragma unroll
    for (int kt = 0; kt < 8; kt++) bfrag[kt] = nbf[kt];
#pragma unroll
    for (int mt = 0; mt < 4; mt++) tk[mt] = ntk[mt];
    agf = nagf;
    const float Uv = nUv, gamv = ngam, grcv = ngrc;
    // ---- issue NEXT chunk's loads; they drain under this iteration ----
    const int cn = (c + 1 < NC_) ? c + 1 : c;
    SCAN_LOAD(cn);
    // ---- phase A: dump S to LDS; stage gamma tables ----
    if (tid < 32) { gam[tid] = gamv; grc[tid] = grcv; }
#pragma unroll
    for (int mt = 0; mt < 4; mt++) {
      ushort4 p;
      p.x = f2bf(acc[mt][0]); p.y = f2bf(acc[mt][1]);
      p.z = f2bf(acc[mt][2]); p.w = f2bf(acc[mt][3]);
      *(ushort4*)&S_A[l15 * 520 + w * 64 + mt * 16 + quad * 4] = p;
    }
    __syncthreads();
    // ---- phase B: one MFMA task per wave (8 MFMAs over its k-half) ----
    f32x4 g = (f32x4){0.f, 0.f, 0.f, 0.f};
#pragma unroll
    for (int kt = 0; kt < 8; kt++) {
      short8 af = *(const short8*)&S_A[l15 * 520 + khalf * 256 + kt * 32 + quad * 8];
      g = __builtin_amdgcn_mfma_f32_16x16x32_bf16(af, bfrag[kt], g, 0, 0, 0);
    }
    *(f32x4*)&P[mat][khalf][ttile * 16 + l15][quad * 4] = g;
    __syncthreads();
    // ---- phase C: 2-way reduce, C~ = U - T1, OB = gam*T2 ----
    const float gCs = gam[31];
    {
      const float T1 = P[0][0][ct][cv] + P[0][1][ct][cv];
      const float T2 = P[1][0][ct][cv] + P[1][1][ct][cv];
      const float ctv = Uv - T1;
      Ct_T[cv * 40 + ct] = f2bf(ctv);
      Cr_T[cv * 40 + ct] = f2bf(ctv * grc[ct]);
      OB[ct][cv] = gam[ct] * T2;
    }
    __syncthreads();
    // ---- phase F: state update (all waves); O GEMM (waves 0,1) -> gdn ----
    short8 bcf = *(const short8*)&Cr_T[l15 * 40 + quad * 8];
#pragma unroll
    for (int mt = 0; mt < 4; mt++) {
      acc[mt] = acc[mt] * gCs;
      acc[mt] = __builtin_amdgcn_mfma_f32_16x16x32_bf16(tk[mt], bcf, acc[mt], 0, 0, 0);
    }
    if (w < 2) {
      short8 ctf = *(const short8*)&Ct_T[l15 * 40 + quad * 8];
      f32x4 oo;
#pragma unroll
      for (int r = 0; r < 4; r++) oo[r] = OB[w * 16 + quad * 4 + r][l15];
      oo = __builtin_amdgcn_mfma_f32_16x16x32_bf16(agf, ctf, oo, 0, 0, 0);
#pragma unroll
      for (int r = 0; r < 4; r++)
        gdn[(bS + t0 + w * 16 + quad * 4 + r) * 512 + iv0 + l15] = oo[r];
    }
  }
#undef SCAN_LOAD
}

// ---------------------------------------------------------------------------
// zero-centered rmsnorm * norm_w * silu(gate) -> bf16 h
// ---------------------------------------------------------------------------
__global__ __launch_bounds__(256) void norm_gate(
    const float* __restrict__ gdn, const float* __restrict__ lg,
    const float* __restrict__ nw, u16* __restrict__ h)
{
  __shared__ float red[8];
  const int row = blockIdx.x, tid = threadIdx.x;
  const size_t base = (size_t)row * D_;
  const float g0 = gdn[base + tid], g1 = gdn[base + tid + 256];
  float sm = g0 + g1;
#pragma unroll
  for (int m = 32; m >= 1; m >>= 1) sm += __shfl_xor(sm, m, 64);
  if ((tid & 63) == 0) red[tid >> 6] = sm;
  __syncthreads();
  const float mean = (red[0] + red[1] + red[2] + red[3]) * (1.0f / 512.0f);
  const float x0 = g0 - mean, x1 = g1 - mean;
  float sq = x0 * x0 + x1 * x1;
#pragma unroll
  for (int m = 32; m >= 1; m >>= 1) sq += __shfl_xor(sq, m, 64);
  if ((tid & 63) == 0) red[4 + (tid >> 6)] = sq;
  __syncthreads();
  const float var = (red[4] + red[5] + red[6] + red[7]) * (1.0f / 512.0f);
  const float rst = rsqrtf(var + 1e-5f);
  const float gl0 = lg[base + tid];
  h[base + tid] = f2bf(x0 * rst * nw[tid] * (gl0 * sigm(gl0)));
  const float gl1 = lg[base + tid + 256];
  h[base + tid + 256] = f2bf(x1 * rst * nw[tid + 256] * (gl1 * sigm(gl1)));
}

// ---------------------------------------------------------------------------
extern "C" void kernel_launch(void* const* d_in, const int* in_sizes, int n_in,
                              void* d_out, int out_size, void* d_ws, size_t ws_size,
                              hipStream_t stream)
{
  const float* x   = (const float*)d_in[0];
  const float* Wq  = (const float*)d_in[1];
  const float* bq  = (const float*)d_in[2];
  const float* Wk  = (const float*)d_in[3];
  const float* bk  = (const float*)d_in[4];
  const float* Wv  = (const float*)d_in[5];
  const float* bv  = (const float*)d_in[6];
  const float* Wa  = (const float*)d_in[7];
  const float* ba  = (const float*)d_in[8];
  const float* Wb  = (const float*)d_in[9];
  const float* bb  = (const float*)d_in[10];
  const float* cwq = (const float*)d_in[11];
  const float* cbq = (const float*)d_in[12];
  const float* cwk = (const float*)d_in[13];
  const float* cbk = (const float*)d_in[14];
  const float* cwv = (const float*)d_in[15];
  const float* cbv = (const float*)d_in[16];
  const float* nw  = (const float*)d_in[17];
  const float* Wg  = (const float*)d_in[18];
  const float* bg  = (const float*)d_in[19];
  const float* Wo  = (const float*)d_in[20];
  const float* bo  = (const float*)d_in[21];

  float* ws    = (float*)d_ws;
  float* lin_q = ws;               // f32; reused as gdn after conv
  float* lin_k = ws + ND_;         // f32; reused as khT/Ag/gg after conv
  float* lin_v = ws + 2 * ND_;     // f32; reused as Wc (prepass), then h
  float* lin_g = ws + 3 * ND_;
  float* vb    = ws + 4 * ND_;     // f32 v; overwritten IN PLACE by U in prepass
  u16*   qh    = (u16*)(ws + 5 * ND_);   // ND_ u16
  u16*   kh    = qh + ND_;               // ND_ u16
  float* alpha = ws + 6 * ND_;
  float* beta  = alpha + N_;
  u16*   xb    = (u16*)(beta + N_);
  u16*   wq_b  = xb + ND_;
  u16*   wk_b  = wq_b + 512 * 512;
  u16*   wv_b  = wk_b + 512 * 512;
  u16*   wg_b  = wv_b + 512 * 512;
  u16*   wo_b  = wg_b + 512 * 512;

  u16*   khT   = (u16*)lin_k;            // ND_ u16 (16MB)
  u16*   Agb   = khT + ND_;              // 512*1024 u16 (1MB)
  float* ggb   = (float*)(Agb + (size_t)512 * 1024);  // 512*64 f32
  u16*   Wcb   = (u16*)lin_v;            // 512*32*512 u16 (16MB)
  float* gdn   = lin_q;
  u16*   h     = (u16*)lin_v;            // written after Wc consumed

  const int NW = 512 * 512;
  cvt_bf16<<<(int)(ND_ / 1024), 256, 0, stream>>>(x, xb, (int)ND_);
  cvt_w5<<<dim3(NW / 1024, 5), 256, 0, stream>>>(Wq, Wk, Wv, Wg, Wo, wq_b);

  // fused Q/K/V/G input GEMMs: one launch, 2048 blocks (8/CU)
  gemm_bt4<<<dim3(128, 4, 4), 256, 0, stream>>>(xb, wq_b, bq, bk, bv, bg, ws);
  ab_kernel<<<N_ / 4, 256, 0, stream>>>(x, Wa, ba, Wb, bb, alpha, beta);
  conv_act<<<dim3(N_ / TB_, 3), 256, 0, stream>>>(lin_q, lin_k, lin_v,
                                                  cwq, cbq, cwk, cbk, cwv, cbv, qh, kh, vb);
  transpose_k<<<dim3(S_ / 64, D_ / 64, B_), 256, 0, stream>>>(kh, khT);
  prepass<<<B_ * NC_, 256, 0, stream>>>(kh, qh, vb, alpha, beta, Agb, ggb, Wcb);
  scan_chunk<<<256, 512, 0, stream>>>(qh, khT, Wcb, vb, Agb, ggb, gdn);
  norm_gate<<<N_, 256, 0, stream>>>(gdn, lin_g, nw, h);
  gemm_bt<<<dim3(128, 4), 256, 0, stream>>>(h, wo_b, bo, (float*)d_out);
}

// Round 15
// 469.086 us; speedup vs baseline: 1.0959x; 1.0144x over previous
//
#include <hip/hip_runtime.h>
#include <math.h>

typedef unsigned short u16;
typedef unsigned int u32;
typedef short short8 __attribute__((ext_vector_type(8)));
typedef float f32x4 __attribute__((ext_vector_type(4)));

#define B_ 8
#define S_ 2048
#define D_ 512
#define N_ (B_ * S_)
#define ND_ ((size_t)N_ * D_)
#define CC_ 32              // chunk length (champion config)
#define NC_ (S_ / CC_)      // 64 chunks
#define SV_ 16              // v-rows per scan block
#define TB_ 8               // conv rows per block

__device__ __forceinline__ u16 f2bf(float f) {
  union { float f; u32 i; } v; v.f = f;
  u32 i = v.i;
  i += 0x7FFFu + ((i >> 16) & 1u);   // round-to-nearest-even
  return (u16)(i >> 16);
}
__device__ __forceinline__ float bf2f(u16 u) {
  union { u32 i; float f; } v; v.i = ((u32)u) << 16; return v.f;
}
__device__ __forceinline__ float sigm(float x) { return 1.0f / (1.0f + expf(-x)); }

__device__ __forceinline__ void glds16(const u16* g, u16* l) {
  __builtin_amdgcn_global_load_lds(
      (const __attribute__((address_space(1))) void*)g,
      (__attribute__((address_space(3))) void*)l, 16, 0, 0);
}

// ---------------------------------------------------------------------------
// fused: f32 -> bf16 conversion of x AND alpha/beta row-dots.
// grid: ND_/1024 = 8192 blocks; block bx covers rows 2bx, 2bx+1.
// waves 0,1 -> row 2bx; waves 2,3 -> row 2bx+1.
// ---------------------------------------------------------------------------
__global__ __launch_bounds__(256) void cvt_ab(
    const float* __restrict__ x, u16* __restrict__ xb,
    const float* __restrict__ Wa, const float* __restrict__ ba,
    const float* __restrict__ Wb, const float* __restrict__ bb,
    float* __restrict__ alpha, float* __restrict__ beta)
{
  __shared__ float redA[4], redB[4];
  const int tid = threadIdx.x;
  const int i = (blockIdx.x * 256 + tid) * 4;
  const float4 v = *(const float4*)(x + i);
  ushort4 o;
  o.x = f2bf(v.x); o.y = f2bf(v.y); o.z = f2bf(v.z); o.w = f2bf(v.w);
  *(ushort4*)(xb + i) = o;
  const int col = (tid & 127) * 4;
  const float4 wa = *(const float4*)(Wa + col);
  const float4 wb = *(const float4*)(Wb + col);
  float da = v.x*wa.x + v.y*wa.y + v.z*wa.z + v.w*wa.w;
  float db = v.x*wb.x + v.y*wb.y + v.z*wb.z + v.w*wb.w;
#pragma unroll
  for (int m = 32; m >= 1; m >>= 1) { da += __shfl_xor(da, m, 64); db += __shfl_xor(db, m, 64); }
  if ((tid & 63) == 0) { redA[tid >> 6] = da; redB[tid >> 6] = db; }
  __syncthreads();
  if (tid == 0) {
    const int row = blockIdx.x * 2;
    alpha[row] = sigm(redA[0] + redA[1] + ba[0]);
    beta[row]  = sigm(redB[0] + redB[1] + bb[0]);
  } else if (tid == 128) {
    const int row = blockIdx.x * 2 + 1;
    alpha[row] = sigm(redA[2] + redA[3] + ba[0]);
    beta[row]  = sigm(redB[2] + redB[3] + bb[0]);
  }
}

// ---------------------------------------------------------------------------
// fused f32 -> bf16 for the five 512x512 weight matrices (contiguous dst)
// ---------------------------------------------------------------------------
__global__ __launch_bounds__(256) void cvt_w5(
    const float* __restrict__ w0, const float* __restrict__ w1,
    const float* __restrict__ w2, const float* __restrict__ w3,
    const float* __restrict__ w4, u16* __restrict__ d)
{
  const int z = blockIdx.y;
  const float* s = (z == 0) ? w0 : (z == 1) ? w1 : (z == 2) ? w2 : (z == 3) ? w3 : w4;
  u16* o = d + (size_t)z * 512 * 512;
  const int i = (blockIdx.x * 256 + threadIdx.x) * 4;
  const float4 v = *(const float4*)(s + i);
  ushort4 t;
  t.x = f2bf(v.x); t.y = f2bf(v.y); t.z = f2bf(v.z); t.w = f2bf(v.w);
  *(ushort4*)(o + i) = t;
}

// ---------------------------------------------------------------------------
// GEMM core: 128x128 tile; staging via global_load_lds width=16 with k-slot
// XOR swizzle pre-applied to the global source. obf=1 -> bf16 output.
// ---------------------------------------------------------------------------
__device__ __forceinline__ void gemm_body(
    const u16* __restrict__ A, const u16* __restrict__ W,
    const float* __restrict__ bias, float* __restrict__ out,
    int m0, int n0, u16* As, u16* Bs, int obf)
{
  const int tid = threadIdx.x;
  const int lane = tid & 63, wave = tid >> 6;
  const int wm = (wave >> 1) * 64, wn = (wave & 1) * 64;
  const int l15 = lane & 15, quad = lane >> 4;

  const int lr = tid >> 2;
  const int ks = (tid & 3) ^ ((tid >> 3) & 3);
  u16* abase0 = As + wave * 512;
  u16* abase1 = As + 2048 + wave * 512;
  u16* bbase0 = Bs + wave * 512;
  u16* bbase1 = Bs + 2048 + wave * 512;

  f32x4 acc[4][4];
#pragma unroll
  for (int i = 0; i < 4; i++)
#pragma unroll
    for (int j = 0; j < 4; j++) acc[i][j] = (f32x4){0.f, 0.f, 0.f, 0.f};

  for (int k0 = 0; k0 < 512; k0 += 32) {
    __syncthreads();
    glds16(A + (size_t)(m0 + lr) * 512 + k0 + ks * 8, abase0);
    glds16(A + (size_t)(m0 + 64 + lr) * 512 + k0 + ks * 8, abase1);
    glds16(W + (size_t)(n0 + lr) * 512 + k0 + ks * 8, bbase0);
    glds16(W + (size_t)(n0 + 64 + lr) * 512 + k0 + ks * 8, bbase1);
    __syncthreads();
    short8 af[4], bf[4];
#pragma unroll
    for (int mt = 0; mt < 4; mt++) {
      const int row = wm + mt * 16 + l15;
      af[mt] = *(const short8*)(As + row * 32 + ((quad ^ ((row >> 1) & 3)) * 8));
    }
#pragma unroll
    for (int nt = 0; nt < 4; nt++) {
      const int row = wn + nt * 16 + l15;
      bf[nt] = *(const short8*)(Bs + row * 32 + ((quad ^ ((row >> 1) & 3)) * 8));
    }
#pragma unroll
    for (int mt = 0; mt < 4; mt++)
#pragma unroll
      for (int nt = 0; nt < 4; nt++)
        acc[mt][nt] = __builtin_amdgcn_mfma_f32_16x16x32_bf16(af[mt], bf[nt], acc[mt][nt], 0, 0, 0);
  }
#pragma unroll
  for (int mt = 0; mt < 4; mt++) {
#pragma unroll
    for (int nt = 0; nt < 4; nt++) {
      const int col = n0 + wn + nt * 16 + l15;
      const float bcol = bias[col];
#pragma unroll
      for (int r = 0; r < 4; r++) {
        const int row = m0 + wm + mt * 16 + quad * 4 + r;
        const float val = acc[mt][nt][r] + bcol;
        if (obf) ((u16*)out)[(size_t)row * 512 + col] = f2bf(val);
        else     out[(size_t)row * 512 + col] = val;
      }
    }
  }
}

__global__ __launch_bounds__(256) void gemm_bt(
    const u16* __restrict__ A, const u16* __restrict__ W,
    const float* __restrict__ bias, float* __restrict__ out)
{
  __shared__ u16 As[128 * 32];
  __shared__ u16 Bs[128 * 32];
  gemm_body(A, W, bias, out, blockIdx.x * 128, blockIdx.y * 128, As, Bs, 0);
}

// Batched: z in [0,4) selects {Wq,Wk,Wv,Wg}; z==3 (gate) writes bf16.
__global__ __launch_bounds__(256) void gemm_bt4(
    const u16* __restrict__ A, const u16* __restrict__ Wbase,
    const float* __restrict__ b0, const float* __restrict__ b1,
    const float* __restrict__ b2, const float* __restrict__ b3,
    float* __restrict__ outbase)
{
  __shared__ u16 As[128 * 32];
  __shared__ u16 Bs[128 * 32];
  const int z = blockIdx.z;
  const u16* W = Wbase + (size_t)z * 512 * 512;
  const float* bias = (z == 0) ? b0 : (z == 1) ? b1 : (z == 2) ? b2 : b3;
  float* out = outbase + (size_t)z * ND_;
  gemm_body(A, W, bias, out, blockIdx.x * 128, blockIdx.y * 128, As, Bs, z == 3 ? 1 : 0);
}

// ---------------------------------------------------------------------------
// causal depthwise conv (k=4) + SiLU (+ L2 norm for q,k -> bf16; v -> f32)
// ---------------------------------------------------------------------------
__global__ __launch_bounds__(256) void conv_act(
    const float* __restrict__ lq, const float* __restrict__ lk, const float* __restrict__ lv,
    const float* __restrict__ cwq, const float* __restrict__ cbq,
    const float* __restrict__ cwk, const float* __restrict__ cbk,
    const float* __restrict__ cwv, const float* __restrict__ cbv,
    u16* __restrict__ oq, u16* __restrict__ ok, float* __restrict__ ov)
{
  __shared__ float red[TB_][4];
  const int z = blockIdx.y;
  const int r0 = blockIdx.x * TB_;
  const int b = r0 / S_, t0 = r0 - b * S_;
  const float* lin = (z == 0) ? lq : (z == 1) ? lk : lv;
  const float* cw = (z == 0) ? cwq : (z == 1) ? cwk : cwv;
  const float* cb = (z == 0) ? cbq : (z == 1) ? cbk : cbv;
  const int tid = threadIdx.x;
  const int lane = tid & 63, wave = tid >> 6;

  float w4[2][4], bias[2];
#pragma unroll
  for (int e = 0; e < 2; e++) {
    const int ch = tid + e * 256;
    bias[e] = cb[ch];
#pragma unroll
    for (int tau = 0; tau < 4; tau++) w4[e][tau] = cw[ch * 4 + tau];
  }
  float win[2][TB_ + 3];
#pragma unroll
  for (int i = 0; i < TB_ + 3; i++) {
    const int tt = t0 - 3 + i;
#pragma unroll
    for (int e = 0; e < 2; e++)
      win[e][i] = (tt >= 0) ? lin[(size_t)(b * S_ + tt) * D_ + tid + e * 256] : 0.f;
  }
  float sv[2][TB_], ssq[TB_];
#pragma unroll
  for (int j = 0; j < TB_; j++) {
    float ss = 0.f;
#pragma unroll
    for (int e = 0; e < 2; e++) {
      float acc = bias[e];
#pragma unroll
      for (int tau = 0; tau < 4; tau++) acc = fmaf(win[e][j + tau], w4[e][tau], acc);
      const float s = acc * sigm(acc);
      sv[e][j] = s; ss = fmaf(s, s, ss);
    }
    ssq[j] = ss;
  }
  if (z < 2) {
#pragma unroll
    for (int j = 0; j < TB_; j++) {
#pragma unroll
      for (int m = 32; m >= 1; m >>= 1) ssq[j] += __shfl_xor(ssq[j], m, 64);
    }
    if (lane == 0) {
#pragma unroll
      for (int j = 0; j < TB_; j++) red[j][wave] = ssq[j];
    }
    __syncthreads();
    u16* outp = (z == 0) ? oq : ok;
#pragma unroll
    for (int j = 0; j < TB_; j++) {
      const float tot = red[j][0] + red[j][1] + red[j][2] + red[j][3];
      const float scale = 1.0f / fmaxf(sqrtf(tot), 1e-12f);
      outp[(size_t)(r0 + j) * D_ + tid] = f2bf(sv[0][j] * scale);
      outp[(size_t)(r0 + j) * D_ + tid + 256] = f2bf(sv[1][j] * scale);
    }
  } else {
#pragma unroll
    for (int j = 0; j < TB_; j++) {
      ov[(size_t)(r0 + j) * D_ + tid] = sv[0][j];
      ov[(size_t)(r0 + j) * D_ + tid + 256] = sv[1][j];
    }
  }
}

// ---------------------------------------------------------------------------
// transpose kh [b,t,ch] -> khT [b,ch,t]  (bf16), 64x64 tiles
// ---------------------------------------------------------------------------
__global__ __launch_bounds__(256) void transpose_k(
    const u16* __restrict__ kh, u16* __restrict__ khT)
{
  __shared__ u16 T[64][68];
  const int b = blockIdx.z;
  const int t0 = blockIdx.x * 64;
  const int c0 = blockIdx.y * 64;
  const int tid = threadIdx.x;
  const int tr = tid >> 4;
  const int c4 = (tid & 15) * 4;
#pragma unroll
  for (int i = 0; i < 4; i++) {
    const int t = tr + i * 16;
    ushort4 v = *(const ushort4*)(kh + ((size_t)(b * S_ + t0 + t)) * 512 + c0 + c4);
    T[c4 + 0][t] = v.x; T[c4 + 1][t] = v.y; T[c4 + 2][t] = v.z; T[c4 + 3][t] = v.w;
  }
  __syncthreads();
#pragma unroll
  for (int i = 0; i < 4; i++) {
    const int ch = tr + i * 16;
    ushort4 v = *(const ushort4*)&T[ch][c4];
    *(ushort4*)(khT + ((size_t)(b * 512 + c0 + ch)) * S_ + t0 + c4) = v;
  }
}

// ---------------------------------------------------------------------------
// prepass (CC=32 champion version)
// ---------------------------------------------------------------------------
__global__ __launch_bounds__(256) void prepass(
    const u16* __restrict__ kh, const u16* __restrict__ qh,
    float* __restrict__ vbU,              // in: betaless V (f32); out: U
    const float* __restrict__ alpha, const float* __restrict__ beta,
    u16* __restrict__ Ag, float* __restrict__ gg, u16* __restrict__ Wc)
{
  __shared__ float KK[32][33];
  __shared__ float QK[32][33];
  __shared__ float Ml[32][33];
  __shared__ float Xs[32][33];
  __shared__ u16 Xb[32 * 40];
  __shared__ u16 VT[512 * 40];           // transposed operand [col][s]
  __shared__ float lg[32], cum[32], bet[32], gams[32];
  const int bc = blockIdx.x;
  const int b = bc >> 6, c = bc & 63;
  const int t0 = c * CC_;
  const int tid = threadIdx.x, lane = tid & 63, w = tid >> 6;
  const int l15 = lane & 15, quad = lane >> 4;
  const size_t rb = (size_t)b * S_ + t0;

  if (tid < 32) { lg[tid] = logf(alpha[b * S_ + t0 + tid]); bet[tid] = beta[b * S_ + t0 + tid]; }
  __syncthreads();
  if (tid < 32) {
    float s = 0.f;
    for (int u = 0; u <= tid; u++) s += lg[u];
    cum[tid] = s;
    gams[tid] = expf(s);
  }
  // KK^T and QK^T quadrants
  const int mi = w >> 1, ni = w & 1;
  f32x4 ck = (f32x4){0.f,0.f,0.f,0.f}, cq = ck;
#pragma unroll
  for (int kt = 0; kt < 16; kt++) {
    const int kc = kt * 32 + quad * 8;
    short8 afk = *(const short8*)(kh + (rb + mi * 16 + l15) * 512 + kc);
    short8 afq = *(const short8*)(qh + (rb + mi * 16 + l15) * 512 + kc);
    short8 bk  = *(const short8*)(kh + (rb + ni * 16 + l15) * 512 + kc);
    ck = __builtin_amdgcn_mfma_f32_16x16x32_bf16(afk, bk, ck, 0, 0, 0);
    cq = __builtin_amdgcn_mfma_f32_16x16x32_bf16(afq, bk, cq, 0, 0, 0);
  }
#pragma unroll
  for (int r = 0; r < 4; r++) {
    KK[mi * 16 + quad * 4 + r][ni * 16 + l15] = ck[r];
    QK[mi * 16 + quad * 4 + r][ni * 16 + l15] = cq[r];
  }
  __syncthreads();
  if (tid < 32) {
    gg[(size_t)bc * 64 + tid] = gams[tid];
    gg[(size_t)bc * 64 + 32 + tid] = expf(cum[31] - cum[tid]);
  }
#pragma unroll
  for (int rep = 0; rep < 4; rep++) {
    const int e = tid + rep * 256;
    const int t = e >> 5, s = e & 31;
    const float er = expf(cum[t] - cum[s]);
    Ml[t][s] = (s < t) ? bet[t] * er * KK[t][s] : 0.f;
    Ag[(size_t)bc * 1024 + t * 32 + s] = (s <= t) ? f2bf(QK[t][s] * er) : (u16)0;
  }
  // stage V^T (beta-scaled, bf16) while the solve runs next
#pragma unroll
  for (int rep = 0; rep < 8; rep++) {
    const int e = tid + rep * 256;
    const int v = e & 511, so = e >> 9;
    short8 pk;
#pragma unroll
    for (int j = 0; j < 8; j++) {
      const int s = so * 8 + j;
      pk[j] = (short)f2bf(bet[s] * vbU[(rb + s) * 512 + v]);
    }
    *(short8*)&VT[v * 40 + so * 8] = pk;
  }
  __syncthreads();
  if (w == 0 && lane < 32) {
    const int j = lane;
    Xs[0][j] = (j == 0) ? 1.f : 0.f;
    for (int t = 1; t < 32; t++) {
      float a = (t == j) ? 1.f : 0.f;
      for (int u = 0; u < t; u++) a = fmaf(-Ml[t][u], Xs[u][j], a);
      Xs[t][j] = a;
    }
  }
  __syncthreads();
#pragma unroll
  for (int rep = 0; rep < 4; rep++) {
    const int e = tid + rep * 256;
    const int t = e >> 5, s = e & 31;
    Xb[t * 40 + s] = f2bf(Xs[t][s]);
  }
  __syncthreads();
  // U = X * betaV  (m=t 2 tiles, n = 512 v cols; wave w owns 8 n-tiles)
  short8 xa[2];
  xa[0] = *(const short8*)&Xb[l15 * 40 + quad * 8];
  xa[1] = *(const short8*)&Xb[(16 + l15) * 40 + quad * 8];
#pragma unroll
  for (int ntr = 0; ntr < 8; ntr++) {
    const int nt = w * 8 + ntr;
    short8 bv = *(const short8*)&VT[(nt * 16 + l15) * 40 + quad * 8];
#pragma unroll
    for (int mt = 0; mt < 2; mt++) {
      f32x4 g = (f32x4){0.f, 0.f, 0.f, 0.f};
      g = __builtin_amdgcn_mfma_f32_16x16x32_bf16(xa[mt], bv, g, 0, 0, 0);
#pragma unroll
      for (int r = 0; r < 4; r++)
        vbU[(rb + mt * 16 + quad * 4 + r) * 512 + nt * 16 + l15] = g[r];
    }
  }
  __syncthreads();
  // refill: K^T scaled by beta*gamma (bf16)
#pragma unroll
  for (int rep = 0; rep < 8; rep++) {
    const int e = tid + rep * 256;
    const int v = e & 511, so = e >> 9;
    short8 pk;
#pragma unroll
    for (int j = 0; j < 8; j++) {
      const int s = so * 8 + j;
      pk[j] = (short)f2bf(bet[s] * gams[s] * bf2f(kh[(rb + s) * 512 + v]));
    }
    *(short8*)&VT[v * 40 + so * 8] = pk;
  }
  __syncthreads();
  // Wc = X * beta*diag(gamma)*K  (bf16 out)
#pragma unroll
  for (int ntr = 0; ntr < 8; ntr++) {
    const int nt = w * 8 + ntr;
    short8 bv = *(const short8*)&VT[(nt * 16 + l15) * 40 + quad * 8];
#pragma unroll
    for (int mt = 0; mt < 2; mt++) {
      f32x4 g = (f32x4){0.f, 0.f, 0.f, 0.f};
      g = __builtin_amdgcn_mfma_f32_16x16x32_bf16(xa[mt], bv, g, 0, 0, 0);
#pragma unroll
      for (int r = 0; r < 4; r++)
        Wc[(size_t)bc * 16384 + (mt * 16 + quad * 4 + r) * 512 + nt * 16 + l15] = f2bf(g[r]);
    }
  }
}

// ---------------------------------------------------------------------------
// chunked gated-delta scan (champion: XCD remap + P stride 20)
// ---------------------------------------------------------------------------
__global__ __launch_bounds__(512) void scan_chunk(
    const u16* __restrict__ qh, const u16* __restrict__ khT,
    const u16* __restrict__ Wc, const float* __restrict__ U,
    const u16* __restrict__ Ag, const float* __restrict__ gg,
    float* __restrict__ gdn)
{
  __shared__ u16 S_A[16 * 520];       // S[v][k] bf16
  __shared__ float P[2][2][32][20];   // [mat][khalf][t][v] (pad 20: aligned, conflict-free)
  __shared__ u16 Ct_T[16 * 40];       // C~^T [v][s]
  __shared__ u16 Cr_T[16 * 40];       // C~^T * (gC/gs)
  __shared__ float OB[32][17];        // gamma_t * T2 [t][v]
  __shared__ float gam[32], grc[32];
  const int b = blockIdx.x & 7;                 // XCD-local batch
  const int iv0 = (blockIdx.x >> 3) * SV_;
  const int tid = threadIdx.x, lane = tid & 63, w = tid >> 6;
  const int l15 = lane & 15, quad = lane >> 4;
  const int ttile = w & 1, mat = (w >> 1) & 1, khalf = w >> 2;
  const size_t bS = (size_t)b * S_;
  const int ct = tid >> 4, cv = tid & 15;     // phase-C coords (32x16)

  f32x4 acc[4];
#pragma unroll
  for (int mt = 0; mt < 4; mt++) acc[mt] = (f32x4){0.f, 0.f, 0.f, 0.f};

  // prefetch registers (next chunk)
  short8 nbf[8], ntk[4], nagf = {};
  float nUv = 0.f, ngam = 0.f, ngrc = 0.f;

#define SCAN_LOAD(CN) do {                                                          \
    const int t0n_ = (CN) * CC_;                                                    \
    const int bcn_ = b * 64 + (CN);                                                 \
    const u16* bsrc_ = mat ? (qh + (bS + t0n_ + ttile * 16 + l15) * 512 + khalf * 256) \
                           : (Wc + ((size_t)bcn_ * 32 + ttile * 16 + l15) * 512 + khalf * 256); \
    _Pragma("unroll")                                                               \
    for (int kt_ = 0; kt_ < 8; kt_++)                                               \
      nbf[kt_] = *(const short8*)(bsrc_ + kt_ * 32 + quad * 8);                     \
    _Pragma("unroll")                                                               \
    for (int mt_ = 0; mt_ < 4; mt_++)                                               \
      ntk[mt_] = *(const short8*)(khT + ((size_t)(b * 512 + w * 64 + mt_ * 16 + l15)) * S_ + t0n_ + quad * 8); \
    nUv = U[(bS + t0n_ + ct) * 512 + iv0 + cv];                                     \
    if (w < 2) nagf = *(const short8*)(Ag + (size_t)bcn_ * 1024 + (w * 16 + l15) * 32 + quad * 8); \
    if (tid < 32) { ngam = gg[(size_t)bcn_ * 64 + tid]; ngrc = gg[(size_t)bcn_ * 64 + 32 + tid]; } \
  } while (0)

  SCAN_LOAD(0);

#pragma unroll 1
  for (int c = 0; c < NC_; c++) {
    const int t0 = c * CC_;
    // ---- rotate prefetched regs into current (waitcnt lands here) ----
    short8 bfrag[8], tk[4], agf;
#pragma unroll
    for (int kt = 0; kt < 8; kt++) bfrag[kt] = nbf[kt];
#pragma unroll
    for (int mt = 0; mt < 4; mt++) tk[mt] = ntk[mt];
    agf = nagf;
    const float Uv = nUv, gamv = ngam, grcv = ngrc;
    // ---- issue NEXT chunk's loads; they drain under this iteration ----
    const int cn = (c + 1 < NC_) ? c + 1 : c;
    SCAN_LOAD(cn);
    // ---- phase A: dump S to LDS; stage gamma tables ----
    if (tid < 32) { gam[tid] = gamv; grc[tid] = grcv; }
#pragma unroll
    for (int mt = 0; mt < 4; mt++) {
      ushort4 p;
      p.x = f2bf(acc[mt][0]); p.y = f2bf(acc[mt][1]);
      p.z = f2bf(acc[mt][2]); p.w = f2bf(acc[mt][3]);
      *(ushort4*)&S_A[l15 * 520 + w * 64 + mt * 16 + quad * 4] = p;
    }
    __syncthreads();
    // ---- phase B: one MFMA task per wave (8 MFMAs over its k-half) ----
    f32x4 g = (f32x4){0.f, 0.f, 0.f, 0.f};
#pragma unroll
    for (int kt = 0; kt < 8; kt++) {
      short8 af = *(const short8*)&S_A[l15 * 520 + khalf * 256 + kt * 32 + quad * 8];
      g = __builtin_amdgcn_mfma_f32_16x16x32_bf16(af, bfrag[kt], g, 0, 0, 0);
    }
    *(f32x4*)&P[mat][khalf][ttile * 16 + l15][quad * 4] = g;
    __syncthreads();
    // ---- phase C: 2-way reduce, C~ = U - T1, OB = gam*T2 ----
    const float gCs = gam[31];
    {
      const float T1 = P[0][0][ct][cv] + P[0][1][ct][cv];
      const float T2 = P[1][0][ct][cv] + P[1][1][ct][cv];
      const float ctv = Uv - T1;
      Ct_T[cv * 40 + ct] = f2bf(ctv);
      Cr_T[cv * 40 + ct] = f2bf(ctv * grc[ct]);
      OB[ct][cv] = gam[ct] * T2;
    }
    __syncthreads();
    // ---- phase F: state update (all waves); O GEMM (waves 0,1) -> gdn ----
    short8 bcf = *(const short8*)&Cr_T[l15 * 40 + quad * 8];
#pragma unroll
    for (int mt = 0; mt < 4; mt++) {
      acc[mt] = acc[mt] * gCs;
      acc[mt] = __builtin_amdgcn_mfma_f32_16x16x32_bf16(tk[mt], bcf, acc[mt], 0, 0, 0);
    }
    if (w < 2) {
      short8 ctf = *(const short8*)&Ct_T[l15 * 40 + quad * 8];
      f32x4 oo;
#pragma unroll
      for (int r = 0; r < 4; r++) oo[r] = OB[w * 16 + quad * 4 + r][l15];
      oo = __builtin_amdgcn_mfma_f32_16x16x32_bf16(agf, ctf, oo, 0, 0, 0);
#pragma unroll
      for (int r = 0; r < 4; r++)
        gdn[(bS + t0 + w * 16 + quad * 4 + r) * 512 + iv0 + l15] = oo[r];
    }
  }
#undef SCAN_LOAD
}

// ---------------------------------------------------------------------------
// zero-centered rmsnorm * norm_w * silu(gate) -> bf16 h  (gate now bf16)
// ---------------------------------------------------------------------------
__global__ __launch_bounds__(256) void norm_gate(
    const float* __restrict__ gdn, const u16* __restrict__ lg,
    const float* __restrict__ nw, u16* __restrict__ h)
{
  __shared__ float red[8];
  const int row = blockIdx.x, tid = threadIdx.x;
  const size_t base = (size_t)row * D_;
  const float g0 = gdn[base + tid], g1 = gdn[base + tid + 256];
  float sm = g0 + g1;
#pragma unroll
  for (int m = 32; m >= 1; m >>= 1) sm += __shfl_xor(sm, m, 64);
  if ((tid & 63) == 0) red[tid >> 6] = sm;
  __syncthreads();
  const float mean = (red[0] + red[1] + red[2] + red[3]) * (1.0f / 512.0f);
  const float x0 = g0 - mean, x1 = g1 - mean;
  float sq = x0 * x0 + x1 * x1;
#pragma unroll
  for (int m = 32; m >= 1; m >>= 1) sq += __shfl_xor(sq, m, 64);
  if ((tid & 63) == 0) red[4 + (tid >> 6)] = sq;
  __syncthreads();
  const float var = (red[4] + red[5] + red[6] + red[7]) * (1.0f / 512.0f);
  const float rst = rsqrtf(var + 1e-5f);
  const float gl0 = bf2f(lg[base + tid]);
  h[base + tid] = f2bf(x0 * rst * nw[tid] * (gl0 * sigm(gl0)));
  const float gl1 = bf2f(lg[base + tid + 256]);
  h[base + tid + 256] = f2bf(x1 * rst * nw[tid + 256] * (gl1 * sigm(gl1)));
}

// ---------------------------------------------------------------------------
extern "C" void kernel_launch(void* const* d_in, const int* in_sizes, int n_in,
                              void* d_out, int out_size, void* d_ws, size_t ws_size,
                              hipStream_t stream)
{
  const float* x   = (const float*)d_in[0];
  const float* Wq  = (const float*)d_in[1];
  const float* bq  = (const float*)d_in[2];
  const float* Wk  = (const float*)d_in[3];
  const float* bk  = (const float*)d_in[4];
  const float* Wv  = (const float*)d_in[5];
  const float* bv  = (const float*)d_in[6];
  const float* Wa  = (const float*)d_in[7];
  const float* ba  = (const float*)d_in[8];
  const float* Wb  = (const float*)d_in[9];
  const float* bb  = (const float*)d_in[10];
  const float* cwq = (const float*)d_in[11];
  const float* cbq = (const float*)d_in[12];
  const float* cwk = (const float*)d_in[13];
  const float* cbk = (const float*)d_in[14];
  const float* cwv = (const float*)d_in[15];
  const float* cbv = (const float*)d_in[16];
  const float* nw  = (const float*)d_in[17];
  const float* Wg  = (const float*)d_in[18];
  const float* bg  = (const float*)d_in[19];
  const float* Wo  = (const float*)d_in[20];
  const float* bo  = (const float*)d_in[21];

  float* ws    = (float*)d_ws;
  float* lin_q = ws;               // f32; reused as gdn after conv
  float* lin_k = ws + ND_;         // f32; reused as khT/Ag/gg after conv
  float* lin_v = ws + 2 * ND_;     // f32; reused as Wc (prepass), then h
  float* lin_g = ws + 3 * ND_;     // gate: stored as bf16 (u16, half the slot)
  float* vb    = ws + 4 * ND_;     // f32 v; overwritten IN PLACE by U in prepass
  u16*   qh    = (u16*)(ws + 5 * ND_);   // ND_ u16
  u16*   kh    = qh + ND_;               // ND_ u16
  float* alpha = ws + 6 * ND_;
  float* beta  = alpha + N_;
  u16*   xb    = (u16*)(beta + N_);
  u16*   wq_b  = xb + ND_;
  u16*   wk_b  = wq_b + 512 * 512;
  u16*   wv_b  = wk_b + 512 * 512;
  u16*   wg_b  = wv_b + 512 * 512;
  u16*   wo_b  = wg_b + 512 * 512;

  u16*   khT   = (u16*)lin_k;            // ND_ u16 (16MB)
  u16*   Agb   = khT + ND_;              // 512*1024 u16 (1MB)
  float* ggb   = (float*)(Agb + (size_t)512 * 1024);  // 512*64 f32
  u16*   Wcb   = (u16*)lin_v;            // 512*32*512 u16 (16MB)
  float* gdn   = lin_q;
  u16*   h     = (u16*)lin_v;            // written after Wc consumed

  const int NW = 512 * 512;
  cvt_ab<<<(int)(ND_ / 1024), 256, 0, stream>>>(x, xb, Wa, ba, Wb, bb, alpha, beta);
  cvt_w5<<<dim3(NW / 1024, 5), 256, 0, stream>>>(Wq, Wk, Wv, Wg, Wo, wq_b);

  // fused Q/K/V/G input GEMMs: one launch, 2048 blocks (8/CU); G -> bf16
  gemm_bt4<<<dim3(128, 4, 4), 256, 0, stream>>>(xb, wq_b, bq, bk, bv, bg, ws);
  conv_act<<<dim3(N_ / TB_, 3), 256, 0, stream>>>(lin_q, lin_k, lin_v,
                                                  cwq, cbq, cwk, cbk, cwv, cbv, qh, kh, vb);
  transpose_k<<<dim3(S_ / 64, D_ / 64, B_), 256, 0, stream>>>(kh, khT);
  prepass<<<B_ * NC_, 256, 0, stream>>>(kh, qh, vb, alpha, beta, Agb, ggb, Wcb);
  scan_chunk<<<256, 512, 0, stream>>>(qh, khT, Wcb, vb, Agb, ggb, gdn);
  norm_gate<<<N_, 256, 0, stream>>>(gdn, (const u16*)lin_g, nw, h);
  gemm_bt<<<dim3(128, 4), 256, 0, stream>>>(h, wo_b, bo, (float*)d_out);
}